// Round 12
// baseline (1244.648 us; speedup 1.0000x reference)
//
#include <hip/hip_runtime.h>
#include <hip/hip_bf16.h>

typedef unsigned short ushort_t;
typedef unsigned int uint_t;

typedef float f32x4 __attribute__((ext_vector_type(4)));
typedef short s16x8 __attribute__((ext_vector_type(8)));

#define HW 56
#define NTOK 3136           // 56*56
#define CDIM 512
#define NHEAD 8
#define CH 64
#define QKVC 1536
#define HID 2048
#define NSEG 14
#define SEGLEN 224          // NTOK / NSEG

// packed tap-major weight buffer layout (floats):
// [0,4608)      cpe 3x3:  [i*512 + c]           i<9,  c<512
// [4608,5760)   crpe 3x3: [4608 + i*128 + c]    i<9,  c<128
// [5760,10560)  crpe 5x5: [5760 + i*192 + c]    i<25, c<192
// [10560,19968) crpe 7x7: [10560 + i*192 + c]   i<49, c<192
// [19968,19976) zeros (zero-page for OOB loads)
#define WPK_TOTAL 19976

__device__ __forceinline__ float b2f(ushort_t u) {
    union { uint_t i; float f; } cv; cv.i = ((uint_t)u) << 16; return cv.f;
}
__device__ __forceinline__ ushort_t f2b(float f) {
    union { __hip_bfloat16 h; ushort_t u; } cv; cv.h = __float2bfloat16(f); return cv.u;
}
__device__ __forceinline__ uint_t pk2(float a, float b) {
    return (uint_t)f2b(a) | ((uint_t)f2b(b) << 16);
}

// fast GELU (tanh approximation): max abs error vs exact-erf ~1e-3, two orders
// below the 0.03125 absmax budget; ~8 VALU ops vs erff's ~25-30 (fc1 epilogue
// runs 16384 of these per block -> ~15-20% of kernel cycles at R11's VALUBusy=42%).
__device__ __forceinline__ float gelu_fast(float x) {
    float u = x * 0.7978845608f * (1.f + 0.044715f * x * x);
    u = fminf(fmaxf(u, -10.f), 10.f);          // tanh saturated; avoids inf/inf
    float e = __expf(2.f * u);
    float th = (e - 1.f) / (e + 1.f);
    return 0.5f * x * (1.f + th);
}

// async global->LDS DMA, 16B per lane. LDS dest is wave-uniform base + lane*16.
__device__ __forceinline__ void gload_lds16(const ushort_t* g, ushort_t* l) {
    __builtin_amdgcn_global_load_lds(
        (const __attribute__((address_space(1))) void*)g,
        (__attribute__((address_space(3))) void*)l, 16, 0, 0);
}

// ---------------- transpose W[K][N] (fp32) -> Wt[N][K] (bf16) ----------------
__global__ __launch_bounds__(256) void k_transpose(const float* __restrict__ in,
                                                   ushort_t* __restrict__ out,
                                                   int K, int Npr) {
    __shared__ float tile[32][33];
    int tx = threadIdx.x & 31, ty = threadIdx.x >> 5;   // ty 0..7
    int kb = blockIdx.y * 32, nb = blockIdx.x * 32;
#pragma unroll
    for (int i = 0; i < 4; i++)
        tile[ty + i * 8][tx] = in[(size_t)(kb + ty + i * 8) * Npr + nb + tx];
    __syncthreads();
#pragma unroll
    for (int i = 0; i < 4; i++)
        out[(size_t)(nb + ty + i * 8) * K + kb + tx] = f2b(tile[tx][ty + i * 8]);
}

// ---------------- pack conv weights tap-major + zero page ----------------
__global__ __launch_bounds__(256) void k_wtrans(const float* __restrict__ cpe_w,
                                                const float* __restrict__ w3,
                                                const float* __restrict__ w5,
                                                const float* __restrict__ w7,
                                                float* __restrict__ wpk) {
    int idx = blockIdx.x * 256 + threadIdx.x;
    if (idx < 4608) {
        int i = idx / 512, c = idx % 512;
        wpk[idx] = cpe_w[c * 9 + i];
    } else if (idx < 5760) {
        int r = idx - 4608; int i = r / 128, c = r % 128;
        wpk[idx] = w3[c * 9 + i];
    } else if (idx < 10560) {
        int r = idx - 5760; int i = r / 192, c = r % 192;
        wpk[idx] = w5[c * 25 + i];
    } else if (idx < 19968) {
        int r = idx - 10560; int i = r / 192, c = r % 192;
        wpk[idx] = w7[c * 49 + i];
    } else if (idx < WPK_TOTAL) {
        wpk[idx] = 0.f;
    }
}

// ------- Fused ConvPosEnc + LayerNorm1: x0 = dwconv3x3(x)+b+x; cur = LN(x0) -------
__global__ __launch_bounds__(256) void k_cpe_ln(const float* __restrict__ x,
                                                const float* __restrict__ wpk,
                                                const float* __restrict__ bias,
                                                const float* __restrict__ lnw,
                                                const float* __restrict__ lnb,
                                                float* __restrict__ x0,
                                                ushort_t* __restrict__ cur) {
    int t = threadIdx.x;
    int tok = t >> 7;            // 2 tokens per block
    int tl = t & 127;
    int c0 = tl * 4;
    int bb = blockIdx.y;
    int n = blockIdx.x * 2 + tok;
    int y = n / HW, xx = n % HW;
    const float* xb = x + ((size_t)bb * NTOK) * CDIM + c0;
    const float* zf = wpk + 19968;
    float4 a = *(const float4*)(bias + c0);
#pragma unroll
    for (int i = 0; i < 9; i++) {
        int ky = i / 3 - 1, kx = i % 3 - 1;
        int yy = y + ky, xc = xx + kx;
        bool ok = (unsigned)yy < HW && (unsigned)xc < HW;
        const float* ap = ok ? (xb + (size_t)(yy * HW + xc) * CDIM) : zf;
        float4 d = *(const float4*)ap;
        float4 w = *(const float4*)(wpk + i * 512 + c0);
        a.x += w.x * d.x; a.y += w.y * d.y; a.z += w.z * d.z; a.w += w.w * d.w;
    }
    float4 ctr = *(const float4*)(xb + (size_t)n * CDIM);
    a.x += ctr.x; a.y += ctr.y; a.z += ctr.z; a.w += ctr.w;
    *(float4*)(x0 + ((size_t)bb * NTOK + n) * CDIM + c0) = a;

    // LayerNorm over the token's 512 channels
    float s = a.x + a.y + a.z + a.w;
    float s2 = a.x * a.x + a.y * a.y + a.z * a.z + a.w * a.w;
#pragma unroll
    for (int m = 1; m < 64; m <<= 1) { s += __shfl_xor(s, m); s2 += __shfl_xor(s2, m); }
    __shared__ float rs[4], rs2[4];
    int wid = t >> 6, lane = t & 63;
    if (lane == 0) { rs[wid] = s; rs2[wid] = s2; }
    __syncthreads();
    s = rs[tok * 2] + rs[tok * 2 + 1];
    s2 = rs2[tok * 2] + rs2[tok * 2 + 1];
    float mean = s * (1.f / CDIM);
    float var = s2 * (1.f / CDIM) - mean * mean;
    float rstd = rsqrtf(var + 1e-6f);
    float4 wv = *(const float4*)(lnw + c0);
    float4 bv = *(const float4*)(lnb + c0);
    float o0 = (a.x - mean) * rstd * wv.x + bv.x;
    float o1 = (a.y - mean) * rstd * wv.y + bv.y;
    float o2 = (a.z - mean) * rstd * wv.z + bv.z;
    float o3 = (a.w - mean) * rstd * wv.w + bv.w;
    uint2 ro; ro.x = pk2(o0, o1); ro.y = pk2(o2, o3);
    *(uint2*)(cur + ((size_t)bb * NTOK + n) * CDIM + c0) = ro;
}

// -------- LayerNorm over C=512: fp32 in -> bf16 out, one wave per row --------
__global__ __launch_bounds__(256) void k_ln(const float* __restrict__ in,
                                            const float* __restrict__ w,
                                            const float* __restrict__ b,
                                            ushort_t* __restrict__ out) {
    int wid = threadIdx.x >> 6, lane = threadIdx.x & 63;
    size_t row = (size_t)blockIdx.x * 4 + wid;
    const float* p = in + row * CDIM + lane * 8;
    float4 v0 = *(const float4*)p;
    float4 v1 = *(const float4*)(p + 4);
    float v[8] = { v0.x, v0.y, v0.z, v0.w, v1.x, v1.y, v1.z, v1.w };
    float s = 0.f, s2 = 0.f;
#pragma unroll
    for (int i = 0; i < 8; i++) { s += v[i]; s2 += v[i] * v[i]; }
#pragma unroll
    for (int m = 1; m < 64; m <<= 1) { s += __shfl_xor(s, m); s2 += __shfl_xor(s2, m); }
    float mean = s * (1.f / CDIM);
    float var = s2 * (1.f / CDIM) - mean * mean;
    float rstd = rsqrtf(var + 1e-6f);
    float4 w0 = *(const float4*)(w + lane * 8);
    float4 w1 = *(const float4*)(w + lane * 8 + 4);
    float4 b0 = *(const float4*)(b + lane * 8);
    float4 b1 = *(const float4*)(b + lane * 8 + 4);
    float wv[8] = { w0.x, w0.y, w0.z, w0.w, w1.x, w1.y, w1.z, w1.w };
    float bv[8] = { b0.x, b0.y, b0.z, b0.w, b1.x, b1.y, b1.z, b1.w };
    float o[8];
#pragma unroll
    for (int i = 0; i < 8; i++) o[i] = (v[i] - mean) * rstd * wv[i] + bv[i];
    uint4 ro;
    ro.x = pk2(o[0], o[1]); ro.y = pk2(o[2], o[3]); ro.z = pk2(o[4], o[5]); ro.w = pk2(o[6], o[7]);
    *(uint4*)(out + row * CDIM + lane * 8) = ro;
}

// ------------- MFMA GEMM 128x128 (R7-proven): out[M,N] = A[M,K] @ Bt[N,K]^T -------------
// 4 waves, BK=64, single-buffer 32KiB LDS, gload_lds + XOR chunk-swizzle (0 conflicts),
// T1 XCD swizzle. 64V+64A regs -> ~3 blocks/CU; inter-block TLP hides the drain.
// R10 A/B: 256x128@512thr variant was NOT better (209 vs 204us) -> this is the local opt.
// EPI 0: store bf16.  EPI 1: +bias +res(fp32), store fp32.  EPI 2: +bias, GELU(fast), store bf16.
template <int EPI>
__global__ __launch_bounds__(256, 3) void k_gemm(const ushort_t* __restrict__ A,
                                                 const ushort_t* __restrict__ Bt,
                                                 const float* __restrict__ bias,
                                                 const float* __restrict__ res,
                                                 void* __restrict__ outv,
                                                 int M, int Npr, int K) {
    __shared__ ushort_t As[128 * 64];
    __shared__ ushort_t Bs[128 * 64];
    int t = threadIdx.x;

    // XCD-aware chunked swizzle (bijective when nwg%8==0; identity otherwise)
    int gx = gridDim.x;
    int bx = blockIdx.x, by = blockIdx.y;
    int nwg = gx * gridDim.y;
    if ((nwg & 7) == 0) {
        int fid = by * gx + bx;
        int cpx = nwg >> 3;
        int swz = (fid & 7) * cpx + (fid >> 3);
        bx = swz % gx; by = swz / gx;
    }
    int m0 = by * 128, n0 = bx * 128;

    int wid = t >> 6, lane = t & 63, q = lane >> 4, r16 = lane & 15;
    int wr = wid >> 1, wc = wid & 1;     // wave grid 2x2; per-wave out 64x64
    f32x4 acc[4][4] = {};

    int srow = lane >> 3;                    // 0..7 == row&7 at the dest
    int scol = ((lane & 7) ^ srow) * 8;      // pre-swizzled source column
    const ushort_t* pA[4];
    const ushort_t* pB[4];
    int lofs[4];
#pragma unroll
    for (int c = 0; c < 4; c++) {
        int rowc = wid * 32 + c * 8 + srow;          // 0..127
        int ra = m0 + rowc; if (ra > M - 1) ra = M - 1;
        pA[c] = A + (size_t)ra * K + scol;
        pB[c] = Bt + (size_t)(n0 + rowc) * K + scol;
        lofs[c] = (wid * 32 + c * 8) * 64;           // wave-uniform LDS base
    }

    for (int k0 = 0; k0 < K; k0 += 64) {
#pragma unroll
        for (int c = 0; c < 4; c++) gload_lds16(pA[c] + k0, &As[lofs[c]]);
#pragma unroll
        for (int c = 0; c < 4; c++) gload_lds16(pB[c] + k0, &Bs[lofs[c]]);
        __syncthreads();
#pragma unroll
        for (int kk = 0; kk < 64; kk += 32) {
            s16x8 a[4], b[4];
#pragma unroll
            for (int i = 0; i < 4; i++) {
                int R = wr * 64 + i * 16 + r16;
                a[i] = *(const s16x8*)&As[R * 64 + ((kk + q * 8) ^ ((R & 7) * 8))];
            }
#pragma unroll
            for (int j = 0; j < 4; j++) {
                int S = wc * 64 + j * 16 + r16;
                b[j] = *(const s16x8*)&Bs[S * 64 + ((kk + q * 8) ^ ((S & 7) * 8))];
            }
#pragma unroll
            for (int mi = 0; mi < 4; mi++)
#pragma unroll
                for (int ni = 0; ni < 4; ni++)
                    acc[mi][ni] = __builtin_amdgcn_mfma_f32_16x16x32_bf16(a[mi], b[ni], acc[mi][ni], 0, 0, 0);
        }
        __syncthreads();
    }

#pragma unroll
    for (int mi = 0; mi < 4; mi++) {
#pragma unroll
        for (int ni = 0; ni < 4; ni++) {
            int col = n0 + wc * 64 + ni * 16 + r16;
            float bv = 0.f;
            if (EPI != 0) bv = bias[col];
#pragma unroll
            for (int r = 0; r < 4; r++) {
                int row = m0 + wr * 64 + mi * 16 + q * 4 + r;
                if (row >= M) continue;
                float xv = acc[mi][ni][r];
                size_t idx = (size_t)row * Npr + col;
                if (EPI == 0) {
                    ((ushort_t*)outv)[idx] = f2b(xv);
                } else if (EPI == 1) {
                    ((float*)outv)[idx] = xv + bv + res[idx];
                } else {
                    ((ushort_t*)outv)[idx] = f2b(gelu_fast(xv + bv));
                }
            }
        }
    }
}

// ------- softmax phase A: per (b, cblk, seg) partial max & sum(exp), ONLINE -------
__global__ __launch_bounds__(256) void k_sm_part(const ushort_t* __restrict__ qkv,
                                                 float* __restrict__ mxp,
                                                 float* __restrict__ ssp) {
    int cblk = blockIdx.x, seg = blockIdx.y, b = blockIdx.z;
    int ch = threadIdx.x & 63, nt = threadIdx.x >> 6;
    int c0 = cblk * 64;
    const ushort_t* base = qkv + (size_t)b * NTOK * QKVC + CDIM + c0 + ch;
    int nbeg = seg * SEGLEN, nend = nbeg + SEGLEN;
    __shared__ float redm[4][64], reds[4][64];
    float mx = -1e30f, sum = 0.f;
    for (int n = nbeg + nt; n < nend; n += 4) {
        float v = b2f(base[(size_t)n * QKVC]);
        float mn = fmaxf(mx, v);
        sum = sum * __expf(mx - mn) + __expf(v - mn);
        mx = mn;
    }
    redm[nt][ch] = mx;
    reds[nt][ch] = sum;
    __syncthreads();
    if (nt == 0) {
        float m = fmaxf(fmaxf(redm[0][ch], redm[1][ch]), fmaxf(redm[2][ch], redm[3][ch]));
        float S = reds[0][ch] * __expf(redm[0][ch] - m)
                + reds[1][ch] * __expf(redm[1][ch] - m)
                + reds[2][ch] * __expf(redm[2][ch] - m)
                + reds[3][ch] * __expf(redm[3][ch] - m);
        size_t o = ((size_t)b * CDIM + c0 + ch) * NSEG + seg;
        mxp[o] = m;
        ssp[o] = S;
    }
}

// ------------- softmax phase B: merge NSEG partials (log-sum-exp) -------------
__global__ __launch_bounds__(512) void k_sm_red(const float* __restrict__ mxp,
                                                const float* __restrict__ ssp,
                                                float* __restrict__ Mx,
                                                float* __restrict__ Sx) {
    int b = blockIdx.x, c = threadIdx.x;
    const float* mp = mxp + ((size_t)b * CDIM + c) * NSEG;
    const float* sp = ssp + ((size_t)b * CDIM + c) * NSEG;
    float m = -1e30f;
#pragma unroll 4
    for (int s = 0; s < NSEG; s++) m = fmaxf(m, mp[s]);
    float S = 0.f;
#pragma unroll 4
    for (int s = 0; s < NSEG; s++) S += sp[s] * __expf(mp[s] - m);
    Mx[b * CDIM + c] = m;
    Sx[b * CDIM + c] = S;
}

// ------------- kv partial: seg-chunk of softmax(k)^T @ v  (64x64 fp32) -------------
__global__ __launch_bounds__(256) void k_kv_part(const ushort_t* __restrict__ qkv,
                                                 const float* __restrict__ Mx,
                                                 float* __restrict__ kvpart) {
    int hd = blockIdx.x, seg = blockIdx.y, b = blockIdx.z;
    int c0 = hd * CH;
    int t = threadIdx.x, tx = t & 15, ty = t >> 4;
    __shared__ float mx[64];
    __shared__ float ek[8][64];
    __shared__ float vv[8][64];
    if (t < 64) mx[t] = Mx[b * CDIM + c0 + t];
    __syncthreads();
    float acc[4][4] = {};
    const ushort_t* kbase = qkv + (size_t)b * NTOK * QKVC + CDIM + c0;
    const ushort_t* vbase = kbase + CDIM;
    int nbeg = seg * SEGLEN;
    for (int n0 = nbeg; n0 < nbeg + SEGLEN; n0 += 8) {
        for (int idx = t; idx < 512; idx += 256) {
            int r = idx >> 6, ch = idx & 63;
            ek[r][ch] = __expf(b2f(kbase[(size_t)(n0 + r) * QKVC + ch]) - mx[ch]);
            vv[r][ch] = b2f(vbase[(size_t)(n0 + r) * QKVC + ch]);
        }
        __syncthreads();
#pragma unroll
        for (int r = 0; r < 8; r++) {
            float ekv[4], vvv[4];
#pragma unroll
            for (int i = 0; i < 4; i++) ekv[i] = ek[r][ty * 4 + i];
#pragma unroll
            for (int j = 0; j < 4; j++) vvv[j] = vv[r][tx * 4 + j];
#pragma unroll
            for (int i = 0; i < 4; i++)
#pragma unroll
                for (int j = 0; j < 4; j++) acc[i][j] += ekv[i] * vvv[j];
        }
        __syncthreads();
    }
    float* outp = kvpart + (((size_t)(b * NHEAD + hd)) * NSEG + seg) * 4096;
#pragma unroll
    for (int i = 0; i < 4; i++)
#pragma unroll
        for (int j = 0; j < 4; j++)
            outp[(size_t)(ty * 4 + i) * CH + tx * 4 + j] = acc[i][j];
}

// ------------- kv reduce: sum NSEG partials, fold scale/Sx -------------
__global__ __launch_bounds__(256) void k_kv_red(const float* __restrict__ kvpart,
                                                const float* __restrict__ Sx,
                                                float* __restrict__ kv) {
    int quad = blockIdx.x, hd = blockIdx.y, b = blockIdx.z;
    int bh = b * NHEAD + hd;
    int t = threadIdx.x;
    const float* basep = kvpart + ((size_t)bh * NSEG) * 4096 + quad * 1024;
    const float scale = 0.125f;   // Ch^-0.5
#pragma unroll
    for (int k = 0; k < 4; k++) {
        int e = k * 256 + t;
        float s = 0.f;
        for (int sg = 0; sg < NSEG; sg++) s += basep[(size_t)sg * 4096 + e];
        int ck = (quad * 1024 + e) >> 6;
        float sinv = scale / Sx[b * CDIM + hd * CH + ck];
        kv[(size_t)bh * 4096 + quad * 1024 + e] = s * sinv;
    }
}

// ---- Fused ConvRelPosEnc + attn: conv_v in LDS, attn = q@kv + q*conv_v ----
// Each head's 64 channels lie entirely in ONE KS region (heads 0-1: 3x3,
// 2-4: 5x5, 5-7: 7x7); per (64-token, head) block the depthwise conv is
// computed into a 16KB LDS tile and consumed directly by the attn epilogue.
// Conv math transcribed from the proven k_conv (rolling tap counter, unroll 1).
template <int KS>
__global__ __launch_bounds__(256) void k_attn_conv(const ushort_t* __restrict__ qkv,
                                                   const float* __restrict__ kv,
                                                   const float* __restrict__ wpk,
                                                   const float* __restrict__ bias,
                                                   int hb,
                                                   ushort_t* __restrict__ conv) {
    constexpr int PAD = KS / 2;
    constexpr int CHOFF = (KS == 3) ? 0 : ((KS == 5) ? 128 : 320);
    constexpr int WBASE = (KS == 3) ? 4608 : ((KS == 5) ? 5760 : 10560);
    constexpr int WSTR = (KS == 3) ? 128 : 192;
    int nb = blockIdx.x, hd = hb + blockIdx.y, b = blockIdx.z;
    int t = threadIdx.x;
    __shared__ float kvl[64 * 64];     // [ck][cv]
    __shared__ float ql[64 * 65];      // [row][ck], padded
    __shared__ float convl[64 * 64];   // [tok][ch] conv result (fp32)

    // stage kv and q (as in the proven k_attn)
    const float* kvsrc = kv + (size_t)(b * NHEAD + hd) * CH * CH;
    for (int idx = t; idx < 4096; idx += 256) kvl[idx] = kvsrc[idx];
    const ushort_t* qbase = qkv + ((size_t)b * NTOK + nb * 64) * QKVC + hd * CH;
    for (int idx = t; idx < 4096; idx += 256) {
        int r = idx >> 6, ck = idx & 63;
        ql[r * 65 + ck] = b2f(qbase[(size_t)r * QKVC + ck]);
    }

    // ---- conv phase: 2 tokens x 8 channels per thread ----
    {
        int g = t & 7;                   // channel group (8 ch)
        int tl = t >> 3;                 // 0..31 token pair
        int crel8 = g * 8;               // channel within head
        int cw = hd * 64 - CHOFF + crel8;     // channel within KS weight block
        const ushort_t* vb = qkv + (size_t)b * NTOK * QKVC + 2 * CDIM + hd * 64 + crel8;
        const ushort_t* zp = (const ushort_t*)(wpk + 19968);
        float4 blo = *(const float4*)(bias + cw);
        float4 bhi = *(const float4*)(bias + cw + 4);
        float acc[2][8];
        int ty_[2], tx_[2];
#pragma unroll
        for (int k2 = 0; k2 < 2; k2++) {
            int n = nb * 64 + tl * 2 + k2;
            ty_[k2] = n / HW; tx_[k2] = n % HW;
            acc[k2][0] = blo.x; acc[k2][1] = blo.y; acc[k2][2] = blo.z; acc[k2][3] = blo.w;
            acc[k2][4] = bhi.x; acc[k2][5] = bhi.y; acc[k2][6] = bhi.z; acc[k2][7] = bhi.w;
        }
        int ky = -PAD, kx = -PAD;
#pragma unroll 1
        for (int i = 0; i < KS * KS; i++) {
            const float* wp = wpk + WBASE + i * WSTR + cw;
            float4 wlo = *(const float4*)wp;
            float4 whi = *(const float4*)(wp + 4);
            float w[8] = { wlo.x, wlo.y, wlo.z, wlo.w, whi.x, whi.y, whi.z, whi.w };
#pragma unroll
            for (int k2 = 0; k2 < 2; k2++) {
                int yy = ty_[k2] + ky, xc = tx_[k2] + kx;
                bool ok = (unsigned)yy < HW && (unsigned)xc < HW;
                const ushort_t* ap = ok ? (vb + (size_t)(yy * HW + xc) * QKVC) : zp;
                uint4 d = *(const uint4*)ap;
                float dv[8];
                dv[0] = b2f((ushort_t)(d.x & 0xffff)); dv[1] = b2f((ushort_t)(d.x >> 16));
                dv[2] = b2f((ushort_t)(d.y & 0xffff)); dv[3] = b2f((ushort_t)(d.y >> 16));
                dv[4] = b2f((ushort_t)(d.z & 0xffff)); dv[5] = b2f((ushort_t)(d.z >> 16));
                dv[6] = b2f((ushort_t)(d.w & 0xffff)); dv[7] = b2f((ushort_t)(d.w >> 16));
#pragma unroll
                for (int j = 0; j < 8; j++) acc[k2][j] += w[j] * dv[j];
            }
            kx++; if (kx > PAD) { kx = -PAD; ky++; }
        }
#pragma unroll
        for (int k2 = 0; k2 < 2; k2++) {
            int tok = tl * 2 + k2;
            float4 lo = { acc[k2][0], acc[k2][1], acc[k2][2], acc[k2][3] };
            float4 hi = { acc[k2][4], acc[k2][5], acc[k2][6], acc[k2][7] };
            *(float4*)&convl[tok * 64 + crel8] = lo;
            *(float4*)&convl[tok * 64 + crel8 + 4] = hi;
        }
    }
    __syncthreads();   // kvl/ql staged + convl complete

    // ---- attn phase (identical math to the proven k_attn) ----
    int tx = t & 15, ty = t >> 4;   // ty 0..15
    float acc[4][4] = {};
    for (int ck = 0; ck < 64; ck++) {
        float kvr[4];
#pragma unroll
        for (int j = 0; j < 4; j++) kvr[j] = kvl[ck * 64 + tx * 4 + j];
#pragma unroll
        for (int i = 0; i < 4; i++) {
            float qv = ql[(ty + 16 * i) * 65 + ck];
#pragma unroll
            for (int j = 0; j < 4; j++) acc[i][j] += qv * kvr[j];
        }
    }
    size_t obase = (size_t)b * NTOK + nb * 64;
#pragma unroll
    for (int i = 0; i < 4; i++) {
        int row = ty + 16 * i;
        size_t o = (obase + row) * CDIM + hd * CH + tx * 4;
        float c0 = convl[row * 64 + tx * 4 + 0];
        float c1 = convl[row * 64 + tx * 4 + 1];
        float c2 = convl[row * 64 + tx * 4 + 2];
        float c3 = convl[row * 64 + tx * 4 + 3];
        float q0 = ql[row * 65 + tx * 4 + 0];
        float q1 = ql[row * 65 + tx * 4 + 1];
        float q2 = ql[row * 65 + tx * 4 + 2];
        float q3 = ql[row * 65 + tx * 4 + 3];
        uint2 ov;
        ov.x = pk2(acc[i][0] + q0 * c0, acc[i][1] + q1 * c1);
        ov.y = pk2(acc[i][2] + q2 * c2, acc[i][3] + q3 * c3);
        *(uint2*)&conv[o] = ov;
    }
}

// ---------------------------------------------------------------------------
extern "C" void kernel_launch(void* const* d_in, const int* in_sizes, int n_in,
                              void* d_out, int out_size, void* d_ws, size_t ws_size,
                              hipStream_t stream) {
    const float* x     = (const float*)d_in[0];
    const float* cpe_w = (const float*)d_in[3];
    const float* cpe_b = (const float*)d_in[4];
    const float* ln1_w = (const float*)d_in[5];
    const float* ln1_b = (const float*)d_in[6];
    const float* qkv_w = (const float*)d_in[7];
    const float* proj_w = (const float*)d_in[8];
    const float* proj_b = (const float*)d_in[9];
    const float* w3 = (const float*)d_in[10];
    const float* b3 = (const float*)d_in[11];
    const float* w5 = (const float*)d_in[12];
    const float* b5 = (const float*)d_in[13];
    const float* w7 = (const float*)d_in[14];
    const float* b7 = (const float*)d_in[15];
    const float* ln2_w = (const float*)d_in[16];
    const float* ln2_b = (const float*)d_in[17];
    const float* fc1_w = (const float*)d_in[18];
    const float* fc1_b = (const float*)d_in[19];
    const float* fc2_w = (const float*)d_in[20];
    const float* fc2_b = (const float*)d_in[21];
    float* out = (float*)d_out;

    char* p = (char*)d_ws;
    ushort_t* wt_qkv  = (ushort_t*)p; p += (size_t)QKVC * CDIM * 2;
    ushort_t* wt_proj = (ushort_t*)p; p += (size_t)CDIM * CDIM * 2;
    ushort_t* wt_fc1  = (ushort_t*)p; p += (size_t)HID * CDIM * 2;
    ushort_t* wt_fc2  = (ushort_t*)p; p += (size_t)CDIM * HID * 2;
    float* wpk = (float*)p; p += 20480 * 4;   // WPK_TOTAL rounded up
    size_t wt_bytes = (size_t)(p - (char*)d_ws);

    k_transpose<<<dim3(QKVC / 32, CDIM / 32), 256, 0, stream>>>(qkv_w, wt_qkv, CDIM, QKVC);
    k_transpose<<<dim3(CDIM / 32, CDIM / 32), 256, 0, stream>>>(proj_w, wt_proj, CDIM, CDIM);
    k_transpose<<<dim3(HID / 32, CDIM / 32), 256, 0, stream>>>(fc1_w, wt_fc1, CDIM, HID);
    k_transpose<<<dim3(CDIM / 32, HID / 32), 256, 0, stream>>>(fc2_w, wt_fc2, HID, CDIM);
    k_wtrans<<<(WPK_TOTAL + 255) / 256, 256, 0, stream>>>(cpe_w, w3, w5, w7, wpk);

    // per-batch bytes
    const size_t per_b = (size_t)NTOK * CDIM * 2               // cur
                       + (size_t)NTOK * HID * 2                // union{conv+qkvb | hid}
                       + (size_t)NHEAD * CH * CH * 4           // kv
                       + (size_t)NHEAD * NSEG * 4096 * 4       // kvpart
                       + (size_t)CDIM * 4 * 2                  // Mx, Sx
                       + (size_t)CDIM * NSEG * 4 * 2;          // mxp, ssp
    int Bc = 16;
    while (Bc > 1 && wt_bytes + (size_t)Bc * per_b > ws_size) Bc >>= 1;

    ushort_t* cur = (ushort_t*)p; p += (size_t)Bc * NTOK * CDIM * 2;
    char* un = p;                 p += (size_t)Bc * NTOK * HID * 2;
    ushort_t* conv = (ushort_t*)un;
    ushort_t* qkvb = (ushort_t*)(un + (size_t)Bc * NTOK * CDIM * 2);
    ushort_t* hid  = (ushort_t*)un;
    float* kvb    = (float*)p; p += (size_t)Bc * NHEAD * CH * CH * 4;
    float* kvpart = (float*)p; p += (size_t)Bc * NHEAD * NSEG * 4096 * 4;
    float* Mx  = (float*)p; p += (size_t)Bc * CDIM * 4;
    float* Sx  = (float*)p; p += (size_t)Bc * CDIM * 4;
    float* mxp = (float*)p; p += (size_t)Bc * CDIM * NSEG * 4;
    float* ssp = (float*)p;

    for (int b0 = 0; b0 < 16; b0 += Bc) {
        int M = Bc * NTOK;
        int gy = (M + 127) / 128;
        const float* xch = x + (size_t)b0 * NTOK * CDIM;
        float* och = out + (size_t)b0 * NTOK * CDIM;
        float* x0 = och;   // fp32 residual backbone lives in the output chunk

        k_cpe_ln<<<dim3(NTOK / 2, Bc), 256, 0, stream>>>(xch, wpk, cpe_b, ln1_w, ln1_b, x0, cur);
        k_gemm<0><<<dim3(QKVC / 128, gy), 256, 0, stream>>>(cur, wt_qkv, nullptr, nullptr, qkvb, M, QKVC, CDIM);
        k_sm_part<<<dim3(8, NSEG, Bc), 256, 0, stream>>>(qkvb, mxp, ssp);
        k_sm_red<<<Bc, 512, 0, stream>>>(mxp, ssp, Mx, Sx);
        k_kv_part<<<dim3(NHEAD, NSEG, Bc), 256, 0, stream>>>(qkvb, Mx, kvpart);
        k_kv_red<<<dim3(4, NHEAD, Bc), 256, 0, stream>>>(kvpart, Sx, kvb);
        k_attn_conv<3><<<dim3(NTOK / 64, 2, Bc), 256, 0, stream>>>(qkvb, kvb, wpk, b3, 0, conv);
        k_attn_conv<5><<<dim3(NTOK / 64, 3, Bc), 256, 0, stream>>>(qkvb, kvb, wpk, b5, 2, conv);
        k_attn_conv<7><<<dim3(NTOK / 64, 3, Bc), 256, 0, stream>>>(qkvb, kvb, wpk, b7, 5, conv);
        k_gemm<1><<<dim3(CDIM / 128, gy), 256, 0, stream>>>(conv, wt_proj, proj_b, x0, x0, M, CDIM, CDIM);
        k_ln<<<M / 4, 256, 0, stream>>>(x0, ln2_w, ln2_b, cur);
        k_gemm<2><<<dim3(HID / 128, gy), 256, 0, stream>>>(cur, wt_fc1, fc1_b, nullptr, hid, M, HID, CDIM);
        k_gemm<1><<<dim3(CDIM / 128, gy), 256, 0, stream>>>(hid, wt_fc2, fc2_b, x0, och, M, CDIM, HID);
    }
}

// Round 13
// 1234.648 us; speedup vs baseline: 1.0081x; 1.0081x over previous
//
#include <hip/hip_runtime.h>
#include <hip/hip_bf16.h>

typedef unsigned short ushort_t;
typedef unsigned int uint_t;

typedef float f32x4 __attribute__((ext_vector_type(4)));
typedef short s16x8 __attribute__((ext_vector_type(8)));

#define HW 56
#define NTOK 3136           // 56*56
#define CDIM 512
#define NHEAD 8
#define CH 64
#define QKVC 1536
#define HID 2048
#define NSEG 28
#define SEGLEN 112          // NTOK / NSEG

// packed tap-major weight buffer layout (floats):
// [0,4608)      cpe 3x3:  [i*512 + c]           i<9,  c<512
// [4608,5760)   crpe 3x3: [4608 + i*128 + c]    i<9,  c<128
// [5760,10560)  crpe 5x5: [5760 + i*192 + c]    i<25, c<192
// [10560,19968) crpe 7x7: [10560 + i*192 + c]   i<49, c<192
// [19968,19976) zeros (zero-page for OOB loads)
#define WPK_TOTAL 19976

__device__ __forceinline__ float b2f(ushort_t u) {
    union { uint_t i; float f; } cv; cv.i = ((uint_t)u) << 16; return cv.f;
}
__device__ __forceinline__ ushort_t f2b(float f) {
    union { __hip_bfloat16 h; ushort_t u; } cv; cv.h = __float2bfloat16(f); return cv.u;
}
__device__ __forceinline__ uint_t pk2(float a, float b) {
    return (uint_t)f2b(a) | ((uint_t)f2b(b) << 16);
}

// fast GELU (tanh approximation): max abs err vs exact-erf ~1e-3, two orders
// below the 0.03125 absmax budget. R12 within-run A/B: fc1 200->196us, FETCH
// 80->59MB, reproducible across all 5 dispatches.
__device__ __forceinline__ float gelu_fast(float x) {
    float u = x * 0.7978845608f * (1.f + 0.044715f * x * x);
    u = fminf(fmaxf(u, -10.f), 10.f);          // tanh saturated; avoids inf/inf
    float e = __expf(2.f * u);
    float th = (e - 1.f) / (e + 1.f);
    return 0.5f * x * (1.f + th);
}

// async global->LDS DMA, 16B per lane. LDS dest is wave-uniform base + lane*16.
__device__ __forceinline__ void gload_lds16(const ushort_t* g, ushort_t* l) {
    __builtin_amdgcn_global_load_lds(
        (const __attribute__((address_space(1))) void*)g,
        (__attribute__((address_space(3))) void*)l, 16, 0, 0);
}

// ---------------- transpose W[K][N] (fp32) -> Wt[N][K] (bf16) ----------------
__global__ __launch_bounds__(256) void k_transpose(const float* __restrict__ in,
                                                   ushort_t* __restrict__ out,
                                                   int K, int Npr) {
    __shared__ float tile[32][33];
    int tx = threadIdx.x & 31, ty = threadIdx.x >> 5;   // ty 0..7
    int kb = blockIdx.y * 32, nb = blockIdx.x * 32;
#pragma unroll
    for (int i = 0; i < 4; i++)
        tile[ty + i * 8][tx] = in[(size_t)(kb + ty + i * 8) * Npr + nb + tx];
    __syncthreads();
#pragma unroll
    for (int i = 0; i < 4; i++)
        out[(size_t)(nb + ty + i * 8) * K + kb + tx] = f2b(tile[tx][ty + i * 8]);
}

// ---------------- pack conv weights tap-major + zero page ----------------
__global__ __launch_bounds__(256) void k_wtrans(const float* __restrict__ cpe_w,
                                                const float* __restrict__ w3,
                                                const float* __restrict__ w5,
                                                const float* __restrict__ w7,
                                                float* __restrict__ wpk) {
    int idx = blockIdx.x * 256 + threadIdx.x;
    if (idx < 4608) {
        int i = idx / 512, c = idx % 512;
        wpk[idx] = cpe_w[c * 9 + i];
    } else if (idx < 5760) {
        int r = idx - 4608; int i = r / 128, c = r % 128;
        wpk[idx] = w3[c * 9 + i];
    } else if (idx < 10560) {
        int r = idx - 5760; int i = r / 192, c = r % 192;
        wpk[idx] = w5[c * 25 + i];
    } else if (idx < 19968) {
        int r = idx - 10560; int i = r / 192, c = r % 192;
        wpk[idx] = w7[c * 49 + i];
    } else if (idx < WPK_TOTAL) {
        wpk[idx] = 0.f;
    }
}

// ------- Fused ConvPosEnc + LayerNorm1: x0 = dwconv3x3(x)+b+x; cur = LN(x0) -------
__global__ __launch_bounds__(256) void k_cpe_ln(const float* __restrict__ x,
                                                const float* __restrict__ wpk,
                                                const float* __restrict__ bias,
                                                const float* __restrict__ lnw,
                                                const float* __restrict__ lnb,
                                                float* __restrict__ x0,
                                                ushort_t* __restrict__ cur) {
    int t = threadIdx.x;
    int tok = t >> 7;            // 2 tokens per block
    int tl = t & 127;
    int c0 = tl * 4;
    int bb = blockIdx.y;
    int n = blockIdx.x * 2 + tok;
    int y = n / HW, xx = n % HW;
    const float* xb = x + ((size_t)bb * NTOK) * CDIM + c0;
    const float* zf = wpk + 19968;
    float4 a = *(const float4*)(bias + c0);
#pragma unroll
    for (int i = 0; i < 9; i++) {
        int ky = i / 3 - 1, kx = i % 3 - 1;
        int yy = y + ky, xc = xx + kx;
        bool ok = (unsigned)yy < HW && (unsigned)xc < HW;
        const float* ap = ok ? (xb + (size_t)(yy * HW + xc) * CDIM) : zf;
        float4 d = *(const float4*)ap;
        float4 w = *(const float4*)(wpk + i * 512 + c0);
        a.x += w.x * d.x; a.y += w.y * d.y; a.z += w.z * d.z; a.w += w.w * d.w;
    }
    float4 ctr = *(const float4*)(xb + (size_t)n * CDIM);
    a.x += ctr.x; a.y += ctr.y; a.z += ctr.z; a.w += ctr.w;
    *(float4*)(x0 + ((size_t)bb * NTOK + n) * CDIM + c0) = a;

    // LayerNorm over the token's 512 channels
    float s = a.x + a.y + a.z + a.w;
    float s2 = a.x * a.x + a.y * a.y + a.z * a.z + a.w * a.w;
#pragma unroll
    for (int m = 1; m < 64; m <<= 1) { s += __shfl_xor(s, m); s2 += __shfl_xor(s2, m); }
    __shared__ float rs[4], rs2[4];
    int wid = t >> 6, lane = t & 63;
    if (lane == 0) { rs[wid] = s; rs2[wid] = s2; }
    __syncthreads();
    s = rs[tok * 2] + rs[tok * 2 + 1];
    s2 = rs2[tok * 2] + rs2[tok * 2 + 1];
    float mean = s * (1.f / CDIM);
    float var = s2 * (1.f / CDIM) - mean * mean;
    float rstd = rsqrtf(var + 1e-6f);
    float4 wv = *(const float4*)(lnw + c0);
    float4 bv = *(const float4*)(lnb + c0);
    float o0 = (a.x - mean) * rstd * wv.x + bv.x;
    float o1 = (a.y - mean) * rstd * wv.y + bv.y;
    float o2 = (a.z - mean) * rstd * wv.z + bv.z;
    float o3 = (a.w - mean) * rstd * wv.w + bv.w;
    uint2 ro; ro.x = pk2(o0, o1); ro.y = pk2(o2, o3);
    *(uint2*)(cur + ((size_t)bb * NTOK + n) * CDIM + c0) = ro;
}

// -------- LayerNorm over C=512: fp32 in -> bf16 out, one wave per row --------
__global__ __launch_bounds__(256) void k_ln(const float* __restrict__ in,
                                            const float* __restrict__ w,
                                            const float* __restrict__ b,
                                            ushort_t* __restrict__ out) {
    int wid = threadIdx.x >> 6, lane = threadIdx.x & 63;
    size_t row = (size_t)blockIdx.x * 4 + wid;
    const float* p = in + row * CDIM + lane * 8;
    float4 v0 = *(const float4*)p;
    float4 v1 = *(const float4*)(p + 4);
    float v[8] = { v0.x, v0.y, v0.z, v0.w, v1.x, v1.y, v1.z, v1.w };
    float s = 0.f, s2 = 0.f;
#pragma unroll
    for (int i = 0; i < 8; i++) { s += v[i]; s2 += v[i] * v[i]; }
#pragma unroll
    for (int m = 1; m < 64; m <<= 1) { s += __shfl_xor(s, m); s2 += __shfl_xor(s2, m); }
    float mean = s * (1.f / CDIM);
    float var = s2 * (1.f / CDIM) - mean * mean;
    float rstd = rsqrtf(var + 1e-6f);
    float4 w0 = *(const float4*)(w + lane * 8);
    float4 w1 = *(const float4*)(w + lane * 8 + 4);
    float4 b0 = *(const float4*)(b + lane * 8);
    float4 b1 = *(const float4*)(b + lane * 8 + 4);
    float wv[8] = { w0.x, w0.y, w0.z, w0.w, w1.x, w1.y, w1.z, w1.w };
    float bv[8] = { b0.x, b0.y, b0.z, b0.w, b1.x, b1.y, b1.z, b1.w };
    float o[8];
#pragma unroll
    for (int i = 0; i < 8; i++) o[i] = (v[i] - mean) * rstd * wv[i] + bv[i];
    uint4 ro;
    ro.x = pk2(o[0], o[1]); ro.y = pk2(o[2], o[3]); ro.z = pk2(o[4], o[5]); ro.w = pk2(o[6], o[7]);
    *(uint4*)(out + row * CDIM + lane * 8) = ro;
}

// ------------- MFMA GEMM 128x128 (R7-proven): out[M,N] = A[M,K] @ Bt[N,K]^T -------------
// 4 waves, BK=64, single-buffer 32KiB LDS, gload_lds + XOR chunk-swizzle (0 conflicts),
// T1 XCD swizzle. 64V+64A regs -> ~3 blocks/CU; inter-block TLP hides the drain.
// EPI 0: store bf16.  EPI 1: +bias +res(fp32), store fp32.  EPI 2: +bias, GELU(fast), store bf16.
template <int EPI>
__global__ __launch_bounds__(256, 3) void k_gemm(const ushort_t* __restrict__ A,
                                                 const ushort_t* __restrict__ Bt,
                                                 const float* __restrict__ bias,
                                                 const float* __restrict__ res,
                                                 void* __restrict__ outv,
                                                 int M, int Npr, int K) {
    __shared__ ushort_t As[128 * 64];
    __shared__ ushort_t Bs[128 * 64];
    int t = threadIdx.x;

    // XCD-aware chunked swizzle (bijective when nwg%8==0; identity otherwise)
    int gx = gridDim.x;
    int bx = blockIdx.x, by = blockIdx.y;
    int nwg = gx * gridDim.y;
    if ((nwg & 7) == 0) {
        int fid = by * gx + bx;
        int cpx = nwg >> 3;
        int swz = (fid & 7) * cpx + (fid >> 3);
        bx = swz % gx; by = swz / gx;
    }
    int m0 = by * 128, n0 = bx * 128;

    int wid = t >> 6, lane = t & 63, q = lane >> 4, r16 = lane & 15;
    int wr = wid >> 1, wc = wid & 1;     // wave grid 2x2; per-wave out 64x64
    f32x4 acc[4][4] = {};

    int srow = lane >> 3;                    // 0..7 == row&7 at the dest
    int scol = ((lane & 7) ^ srow) * 8;      // pre-swizzled source column
    const ushort_t* pA[4];
    const ushort_t* pB[4];
    int lofs[4];
#pragma unroll
    for (int c = 0; c < 4; c++) {
        int rowc = wid * 32 + c * 8 + srow;          // 0..127
        int ra = m0 + rowc; if (ra > M - 1) ra = M - 1;
        pA[c] = A + (size_t)ra * K + scol;
        pB[c] = Bt + (size_t)(n0 + rowc) * K + scol;
        lofs[c] = (wid * 32 + c * 8) * 64;           // wave-uniform LDS base
    }

    for (int k0 = 0; k0 < K; k0 += 64) {
#pragma unroll
        for (int c = 0; c < 4; c++) gload_lds16(pA[c] + k0, &As[lofs[c]]);
#pragma unroll
        for (int c = 0; c < 4; c++) gload_lds16(pB[c] + k0, &Bs[lofs[c]]);
        __syncthreads();
#pragma unroll
        for (int kk = 0; kk < 64; kk += 32) {
            s16x8 a[4], b[4];
#pragma unroll
            for (int i = 0; i < 4; i++) {
                int R = wr * 64 + i * 16 + r16;
                a[i] = *(const s16x8*)&As[R * 64 + ((kk + q * 8) ^ ((R & 7) * 8))];
            }
#pragma unroll
            for (int j = 0; j < 4; j++) {
                int S = wc * 64 + j * 16 + r16;
                b[j] = *(const s16x8*)&Bs[S * 64 + ((kk + q * 8) ^ ((S & 7) * 8))];
            }
#pragma unroll
            for (int mi = 0; mi < 4; mi++)
#pragma unroll
                for (int ni = 0; ni < 4; ni++)
                    acc[mi][ni] = __builtin_amdgcn_mfma_f32_16x16x32_bf16(a[mi], b[ni], acc[mi][ni], 0, 0, 0);
        }
        __syncthreads();
    }

#pragma unroll
    for (int mi = 0; mi < 4; mi++) {
#pragma unroll
        for (int ni = 0; ni < 4; ni++) {
            int col = n0 + wc * 64 + ni * 16 + r16;
            float bv = 0.f;
            if (EPI != 0) bv = bias[col];
#pragma unroll
            for (int r = 0; r < 4; r++) {
                int row = m0 + wr * 64 + mi * 16 + q * 4 + r;
                if (row >= M) continue;
                float xv = acc[mi][ni][r];
                size_t idx = (size_t)row * Npr + col;
                if (EPI == 0) {
                    ((ushort_t*)outv)[idx] = f2b(xv);
                } else if (EPI == 1) {
                    ((float*)outv)[idx] = xv + bv + res[idx];
                } else {
                    ((ushort_t*)outv)[idx] = f2b(gelu_fast(xv + bv));
                }
            }
        }
    }
}

// ------- softmax phase A: per (b, cblk, seg) partial max & sum(exp), ONLINE -------
__global__ __launch_bounds__(256) void k_sm_part(const ushort_t* __restrict__ qkv,
                                                 float* __restrict__ mxp,
                                                 float* __restrict__ ssp) {
    int cblk = blockIdx.x, seg = blockIdx.y, b = blockIdx.z;
    int ch = threadIdx.x & 63, nt = threadIdx.x >> 6;
    int c0 = cblk * 64;
    const ushort_t* base = qkv + (size_t)b * NTOK * QKVC + CDIM + c0 + ch;
    int nbeg = seg * SEGLEN, nend = nbeg + SEGLEN;
    __shared__ float redm[4][64], reds[4][64];
    float mx = -1e30f, sum = 0.f;
    for (int n = nbeg + nt; n < nend; n += 4) {
        float v = b2f(base[(size_t)n * QKVC]);
        float mn = fmaxf(mx, v);
        sum = sum * __expf(mx - mn) + __expf(v - mn);
        mx = mn;
    }
    redm[nt][ch] = mx;
    reds[nt][ch] = sum;
    __syncthreads();
    if (nt == 0) {
        float m = fmaxf(fmaxf(redm[0][ch], redm[1][ch]), fmaxf(redm[2][ch], redm[3][ch]));
        float S = reds[0][ch] * __expf(redm[0][ch] - m)
                + reds[1][ch] * __expf(redm[1][ch] - m)
                + reds[2][ch] * __expf(redm[2][ch] - m)
                + reds[3][ch] * __expf(redm[3][ch] - m);
        size_t o = ((size_t)b * CDIM + c0 + ch) * NSEG + seg;
        mxp[o] = m;
        ssp[o] = S;
    }
}

// ------------- softmax phase B: merge NSEG partials (log-sum-exp) -------------
__global__ __launch_bounds__(512) void k_sm_red(const float* __restrict__ mxp,
                                                const float* __restrict__ ssp,
                                                float* __restrict__ Mx,
                                                float* __restrict__ Sx) {
    int b = blockIdx.x, c = threadIdx.x;
    const float* mp = mxp + ((size_t)b * CDIM + c) * NSEG;
    const float* sp = ssp + ((size_t)b * CDIM + c) * NSEG;
    float m = -1e30f;
#pragma unroll 4
    for (int s = 0; s < NSEG; s++) m = fmaxf(m, mp[s]);
    float S = 0.f;
#pragma unroll 4
    for (int s = 0; s < NSEG; s++) S += sp[s] * __expf(mp[s] - m);
    Mx[b * CDIM + c] = m;
    Sx[b * CDIM + c] = S;
}

// ------------- kv partial: seg-chunk of softmax(k)^T @ v  (64x64 fp32) -------------
__global__ __launch_bounds__(256) void k_kv_part(const ushort_t* __restrict__ qkv,
                                                 const float* __restrict__ Mx,
                                                 float* __restrict__ kvpart) {
    int hd = blockIdx.x, seg = blockIdx.y, b = blockIdx.z;
    int c0 = hd * CH;
    int t = threadIdx.x, tx = t & 15, ty = t >> 4;
    __shared__ float mx[64];
    __shared__ float ek[8][64];
    __shared__ float vv[8][64];
    if (t < 64) mx[t] = Mx[b * CDIM + c0 + t];
    __syncthreads();
    float acc[4][4] = {};
    const ushort_t* kbase = qkv + (size_t)b * NTOK * QKVC + CDIM + c0;
    const ushort_t* vbase = kbase + CDIM;
    int nbeg = seg * SEGLEN;
    for (int n0 = nbeg; n0 < nbeg + SEGLEN; n0 += 8) {
        for (int idx = t; idx < 512; idx += 256) {
            int r = idx >> 6, ch = idx & 63;
            ek[r][ch] = __expf(b2f(kbase[(size_t)(n0 + r) * QKVC + ch]) - mx[ch]);
            vv[r][ch] = b2f(vbase[(size_t)(n0 + r) * QKVC + ch]);
        }
        __syncthreads();
#pragma unroll
        for (int r = 0; r < 8; r++) {
            float ekv[4], vvv[4];
#pragma unroll
            for (int i = 0; i < 4; i++) ekv[i] = ek[r][ty * 4 + i];
#pragma unroll
            for (int j = 0; j < 4; j++) vvv[j] = vv[r][tx * 4 + j];
#pragma unroll
            for (int i = 0; i < 4; i++)
#pragma unroll
                for (int j = 0; j < 4; j++) acc[i][j] += ekv[i] * vvv[j];
        }
        __syncthreads();
    }
    float* outp = kvpart + (((size_t)(b * NHEAD + hd)) * NSEG + seg) * 4096;
#pragma unroll
    for (int i = 0; i < 4; i++)
#pragma unroll
        for (int j = 0; j < 4; j++)
            outp[(size_t)(ty * 4 + i) * CH + tx * 4 + j] = acc[i][j];
}

// ------------- kv reduce: sum NSEG partials, fold scale/Sx -------------
__global__ __launch_bounds__(256) void k_kv_red(const float* __restrict__ kvpart,
                                                const float* __restrict__ Sx,
                                                float* __restrict__ kv) {
    int quad = blockIdx.x, hd = blockIdx.y, b = blockIdx.z;
    int bh = b * NHEAD + hd;
    int t = threadIdx.x;
    const float* basep = kvpart + ((size_t)bh * NSEG) * 4096 + quad * 1024;
    const float scale = 0.125f;   // Ch^-0.5
#pragma unroll
    for (int k = 0; k < 4; k++) {
        int e = k * 256 + t;
        float s = 0.f;
        for (int sg = 0; sg < NSEG; sg++) s += basep[(size_t)sg * 4096 + e];
        int ck = (quad * 1024 + e) >> 6;
        float sinv = scale / Sx[b * CDIM + hd * CH + ck];
        kv[(size_t)bh * 4096 + quad * 1024 + e] = s * sinv;
    }
}

// ---- ConvRelPosEnc: uniform-KS depthwise conv on v, R4-proven register profile ----
// 4 tokens/thread, rolling tap counter, #pragma unroll 1 (R6's full unroll spilled).
template <int KS>
__global__ __launch_bounds__(KS == 3 ? 256 : 192) void k_conv(const ushort_t* __restrict__ qkv,
                                                              const float* __restrict__ wpk,
                                                              const float* __restrict__ bias,
                                                              ushort_t* __restrict__ conv) {
    constexpr int PAD = KS / 2;
    constexpr int CHBASE = (KS == 3) ? 0 : ((KS == 5) ? 128 : 320);
    constexpr int WBASE = (KS == 3) ? 4608 : ((KS == 5) ? 5760 : 10560);
    constexpr int WSTR = (KS == 3) ? 128 : 192;
    constexpr int GRP = (KS == 3) ? 16 : 24;     // 8-ch groups in this split
    constexpr int LANES = (KS == 3) ? 16 : 8;    // token-lanes per block
    int t = threadIdx.x;
    int g = t % GRP;            // channel group
    int tl = t / GRP;           // token lane
    int bb = blockIdx.y;
    int n0 = blockIdx.x * (LANES * 4) + tl * 4;
    int crel = g * 8;
    const ushort_t* vb = qkv + (size_t)bb * NTOK * QKVC + 2 * CDIM + CHBASE + crel;
    const ushort_t* zp = (const ushort_t*)(wpk + 19968);
    float4 blo = *(const float4*)(bias + crel);
    float4 bhi = *(const float4*)(bias + crel + 4);
    float acc[4][8];
    int ty[4], txx[4];
#pragma unroll
    for (int k4 = 0; k4 < 4; k4++) {
        int n = n0 + k4; ty[k4] = n / HW; txx[k4] = n % HW;
        acc[k4][0] = blo.x; acc[k4][1] = blo.y; acc[k4][2] = blo.z; acc[k4][3] = blo.w;
        acc[k4][4] = bhi.x; acc[k4][5] = bhi.y; acc[k4][6] = bhi.z; acc[k4][7] = bhi.w;
    }
    int ky = -PAD, kx = -PAD;
#pragma unroll 1
    for (int i = 0; i < KS * KS; i++) {
        const float* wp = wpk + WBASE + i * WSTR + crel;
        float4 wlo = *(const float4*)wp;
        float4 whi = *(const float4*)(wp + 4);
        float w[8] = { wlo.x, wlo.y, wlo.z, wlo.w, whi.x, whi.y, whi.z, whi.w };
#pragma unroll
        for (int k4 = 0; k4 < 4; k4++) {
            int yy = ty[k4] + ky, xc = txx[k4] + kx;
            bool ok = (unsigned)yy < HW && (unsigned)xc < HW;
            const ushort_t* ap = ok ? (vb + (size_t)(yy * HW + xc) * QKVC) : zp;
            uint4 d = *(const uint4*)ap;
            float dv[8];
            dv[0] = b2f((ushort_t)(d.x & 0xffff)); dv[1] = b2f((ushort_t)(d.x >> 16));
            dv[2] = b2f((ushort_t)(d.y & 0xffff)); dv[3] = b2f((ushort_t)(d.y >> 16));
            dv[4] = b2f((ushort_t)(d.z & 0xffff)); dv[5] = b2f((ushort_t)(d.z >> 16));
            dv[6] = b2f((ushort_t)(d.w & 0xffff)); dv[7] = b2f((ushort_t)(d.w >> 16));
#pragma unroll
            for (int j = 0; j < 8; j++) acc[k4][j] += w[j] * dv[j];
        }
        kx++; if (kx > PAD) { kx = -PAD; ky++; }
    }
#pragma unroll
    for (int k4 = 0; k4 < 4; k4++) {
        int n = n0 + k4;
        uint4 o;
        o.x = pk2(acc[k4][0], acc[k4][1]);
        o.y = pk2(acc[k4][2], acc[k4][3]);
        o.z = pk2(acc[k4][4], acc[k4][5]);
        o.w = pk2(acc[k4][6], acc[k4][7]);
        *(uint4*)&conv[((size_t)bb * NTOK + n) * CDIM + CHBASE + crel] = o;
    }
}

// ------------- attn = q @ kv + q * conv_v  (overwrites conv buffer, bf16) -------------
__global__ __launch_bounds__(256) void k_attn(const ushort_t* __restrict__ qkv,
                                              const float* __restrict__ kv,
                                              ushort_t* __restrict__ conv) {
    int nb = blockIdx.x, hd = blockIdx.y, b = blockIdx.z;
    int t = threadIdx.x, tx = t & 15, ty = t >> 4;   // ty 0..15
    __shared__ float kvl[64 * 64];    // [ck][cv]
    __shared__ float ql[64 * 65];     // [row][ck], padded
    const float* kvsrc = kv + (size_t)(b * NHEAD + hd) * CH * CH;
    for (int idx = t; idx < 4096; idx += 256) kvl[idx] = kvsrc[idx];
    const ushort_t* qbase = qkv + ((size_t)b * NTOK + nb * 64) * QKVC + hd * CH;
    for (int idx = t; idx < 4096; idx += 256) {
        int r = idx >> 6, ck = idx & 63;
        ql[r * 65 + ck] = b2f(qbase[(size_t)r * QKVC + ck]);
    }
    __syncthreads();
    float acc[4][4] = {};
    for (int ck = 0; ck < 64; ck++) {
        float kvr[4];
#pragma unroll
        for (int j = 0; j < 4; j++) kvr[j] = kvl[ck * 64 + tx * 4 + j];
#pragma unroll
        for (int i = 0; i < 4; i++) {
            float qv = ql[(ty + 16 * i) * 65 + ck];
#pragma unroll
            for (int j = 0; j < 4; j++) acc[i][j] += qv * kvr[j];
        }
    }
    size_t obase = (size_t)b * NTOK + nb * 64;
#pragma unroll
    for (int i = 0; i < 4; i++) {
        int row = ty + 16 * i;
        size_t o = (obase + row) * CDIM + hd * CH + tx * 4;
        uint2 cv = *(const uint2*)&conv[o];
        float c0 = b2f((ushort_t)(cv.x & 0xffff)), c1 = b2f((ushort_t)(cv.x >> 16));
        float c2 = b2f((ushort_t)(cv.y & 0xffff)), c3 = b2f((ushort_t)(cv.y >> 16));
        float q0 = ql[row * 65 + tx * 4 + 0];
        float q1 = ql[row * 65 + tx * 4 + 1];
        float q2 = ql[row * 65 + tx * 4 + 2];
        float q3 = ql[row * 65 + tx * 4 + 3];
        uint2 ov;
        ov.x = pk2(acc[i][0] + q0 * c0, acc[i][1] + q1 * c1);
        ov.y = pk2(acc[i][2] + q2 * c2, acc[i][3] + q3 * c3);
        *(uint2*)&conv[o] = ov;
    }
}

// ---------------------------------------------------------------------------
extern "C" void kernel_launch(void* const* d_in, const int* in_sizes, int n_in,
                              void* d_out, int out_size, void* d_ws, size_t ws_size,
                              hipStream_t stream) {
    const float* x     = (const float*)d_in[0];
    const float* cpe_w = (const float*)d_in[3];
    const float* cpe_b = (const float*)d_in[4];
    const float* ln1_w = (const float*)d_in[5];
    const float* ln1_b = (const float*)d_in[6];
    const float* qkv_w = (const float*)d_in[7];
    const float* proj_w = (const float*)d_in[8];
    const float* proj_b = (const float*)d_in[9];
    const float* w3 = (const float*)d_in[10];
    const float* b3 = (const float*)d_in[11];
    const float* w5 = (const float*)d_in[12];
    const float* b5 = (const float*)d_in[13];
    const float* w7 = (const float*)d_in[14];
    const float* b7 = (const float*)d_in[15];
    const float* ln2_w = (const float*)d_in[16];
    const float* ln2_b = (const float*)d_in[17];
    const float* fc1_w = (const float*)d_in[18];
    const float* fc1_b = (const float*)d_in[19];
    const float* fc2_w = (const float*)d_in[20];
    const float* fc2_b = (const float*)d_in[21];
    float* out = (float*)d_out;

    char* p = (char*)d_ws;
    ushort_t* wt_qkv  = (ushort_t*)p; p += (size_t)QKVC * CDIM * 2;
    ushort_t* wt_proj = (ushort_t*)p; p += (size_t)CDIM * CDIM * 2;
    ushort_t* wt_fc1  = (ushort_t*)p; p += (size_t)HID * CDIM * 2;
    ushort_t* wt_fc2  = (ushort_t*)p; p += (size_t)CDIM * HID * 2;
    float* wpk = (float*)p; p += 20480 * 4;   // WPK_TOTAL rounded up
    size_t wt_bytes = (size_t)(p - (char*)d_ws);

    k_transpose<<<dim3(QKVC / 32, CDIM / 32), 256, 0, stream>>>(qkv_w, wt_qkv, CDIM, QKVC);
    k_transpose<<<dim3(CDIM / 32, CDIM / 32), 256, 0, stream>>>(proj_w, wt_proj, CDIM, CDIM);
    k_transpose<<<dim3(HID / 32, CDIM / 32), 256, 0, stream>>>(fc1_w, wt_fc1, CDIM, HID);
    k_transpose<<<dim3(CDIM / 32, HID / 32), 256, 0, stream>>>(fc2_w, wt_fc2, HID, CDIM);
    k_wtrans<<<(WPK_TOTAL + 255) / 256, 256, 0, stream>>>(cpe_w, w3, w5, w7, wpk);

    // per-batch bytes
    const size_t per_b = (size_t)NTOK * CDIM * 2               // cur
                       + (size_t)NTOK * HID * 2                // union{conv+qkvb | hid}
                       + (size_t)NHEAD * CH * CH * 4           // kv
                       + (size_t)NHEAD * NSEG * 4096 * 4       // kvpart
                       + (size_t)CDIM * 4 * 2                  // Mx, Sx
                       + (size_t)CDIM * NSEG * 4 * 2;          // mxp, ssp
    int Bc = 16;
    while (Bc > 1 && wt_bytes + (size_t)Bc * per_b > ws_size) Bc >>= 1;

    ushort_t* cur = (ushort_t*)p; p += (size_t)Bc * NTOK * CDIM * 2;
    char* un = p;                 p += (size_t)Bc * NTOK * HID * 2;
    ushort_t* conv = (ushort_t*)un;
    ushort_t* qkvb = (ushort_t*)(un + (size_t)Bc * NTOK * CDIM * 2);
    ushort_t* hid  = (ushort_t*)un;
    float* kvb    = (float*)p; p += (size_t)Bc * NHEAD * CH * CH * 4;
    float* kvpart = (float*)p; p += (size_t)Bc * NHEAD * NSEG * 4096 * 4;
    float* Mx  = (float*)p; p += (size_t)Bc * CDIM * 4;
    float* Sx  = (float*)p; p += (size_t)Bc * CDIM * 4;
    float* mxp = (float*)p; p += (size_t)Bc * CDIM * NSEG * 4;
    float* ssp = (float*)p;

    for (int b0 = 0; b0 < 16; b0 += Bc) {
        int M = Bc * NTOK;
        int gy = (M + 127) / 128;
        const float* xch = x + (size_t)b0 * NTOK * CDIM;
        float* och = out + (size_t)b0 * NTOK * CDIM;
        float* x0 = och;   // fp32 residual backbone lives in the output chunk

        k_cpe_ln<<<dim3(NTOK / 2, Bc), 256, 0, stream>>>(xch, wpk, cpe_b, ln1_w, ln1_b, x0, cur);
        k_gemm<0><<<dim3(QKVC / 128, gy), 256, 0, stream>>>(cur, wt_qkv, nullptr, nullptr, qkvb, M, QKVC, CDIM);
        k_sm_part<<<dim3(8, NSEG, Bc), 256, 0, stream>>>(qkvb, mxp, ssp);
        k_sm_red<<<Bc, 512, 0, stream>>>(mxp, ssp, Mx, Sx);
        k_kv_part<<<dim3(NHEAD, NSEG, Bc), 256, 0, stream>>>(qkvb, Mx, kvpart);
        k_kv_red<<<dim3(4, NHEAD, Bc), 256, 0, stream>>>(kvpart, Sx, kvb);
        k_conv<3><<<dim3(NTOK / 64, Bc), 256, 0, stream>>>(qkvb, wpk, b3, conv);
        k_conv<5><<<dim3(NTOK / 32, Bc), 192, 0, stream>>>(qkvb, wpk, b5, conv);
        k_conv<7><<<dim3(NTOK / 32, Bc), 192, 0, stream>>>(qkvb, wpk, b7, conv);
        k_attn<<<dim3(NTOK / 64, NHEAD, Bc), 256, 0, stream>>>(qkvb, kvb, conv);
        k_gemm<1><<<dim3(CDIM / 128, gy), 256, 0, stream>>>(conv, wt_proj, proj_b, x0, x0, M, CDIM, CDIM);
        k_ln<<<M / 4, 256, 0, stream>>>(x0, ln2_w, ln2_b, cur);
        k_gemm<2><<<dim3(HID / 128, gy), 256, 0, stream>>>(cur, wt_fc1, fc1_b, nullptr, hid, M, HID, CDIM);
        k_gemm<1><<<dim3(CDIM / 128, gy), 256, 0, stream>>>(hid, wt_fc2, fc2_b, x0, och, M, CDIM, HID);
    }
}

// Round 14
// 1210.495 us; speedup vs baseline: 1.0282x; 1.0200x over previous
//
#include <hip/hip_runtime.h>
#include <hip/hip_bf16.h>

typedef unsigned short ushort_t;
typedef unsigned int uint_t;

typedef float f32x4 __attribute__((ext_vector_type(4)));
typedef short s16x8 __attribute__((ext_vector_type(8)));

#define HW 56
#define NTOK 3136           // 56*56
#define CDIM 512
#define NHEAD 8
#define CH 64
#define QKVC 1536
#define HID 2048
#define NSEG 28
#define SEGLEN 112          // NTOK / NSEG

// packed tap-major weight buffer layout (floats):
// [0,4608)      cpe 3x3:  [i*512 + c]           i<9,  c<512
// [4608,5760)   crpe 3x3: [4608 + i*128 + c]    i<9,  c<128
// [5760,10560)  crpe 5x5: [5760 + i*192 + c]    i<25, c<192
// [10560,19968) crpe 7x7: [10560 + i*192 + c]   i<49, c<192
// [19968,19976) zeros (zero-page for OOB loads)
#define WPK_TOTAL 19976

__device__ __forceinline__ float b2f(ushort_t u) {
    union { uint_t i; float f; } cv; cv.i = ((uint_t)u) << 16; return cv.f;
}
__device__ __forceinline__ ushort_t f2b(float f) {
    union { __hip_bfloat16 h; ushort_t u; } cv; cv.h = __float2bfloat16(f); return cv.u;
}
__device__ __forceinline__ uint_t pk2(float a, float b) {
    return (uint_t)f2b(a) | ((uint_t)f2b(b) << 16);
}

// fast GELU (tanh approximation): max abs err vs exact-erf ~1e-3, two orders
// below the 0.03125 absmax budget. R12/R13 within-run A/B: fc1 204->197us,
// FETCH 80->58MB, reproducible across all dispatches.
__device__ __forceinline__ float gelu_fast(float x) {
    float u = x * 0.7978845608f * (1.f + 0.044715f * x * x);
    u = fminf(fmaxf(u, -10.f), 10.f);          // tanh saturated; avoids inf/inf
    float e = __expf(2.f * u);
    float th = (e - 1.f) / (e + 1.f);
    return 0.5f * x * (1.f + th);
}

// async global->LDS DMA, 16B per lane. LDS dest is wave-uniform base + lane*16.
__device__ __forceinline__ void gload_lds16(const ushort_t* g, ushort_t* l) {
    __builtin_amdgcn_global_load_lds(
        (const __attribute__((address_space(1))) void*)g,
        (__attribute__((address_space(3))) void*)l, 16, 0, 0);
}

// ---------------- transpose W[K][N] (fp32) -> Wt[N][K] (bf16) ----------------
__global__ __launch_bounds__(256) void k_transpose(const float* __restrict__ in,
                                                   ushort_t* __restrict__ out,
                                                   int K, int Npr) {
    __shared__ float tile[32][33];
    int tx = threadIdx.x & 31, ty = threadIdx.x >> 5;   // ty 0..7
    int kb = blockIdx.y * 32, nb = blockIdx.x * 32;
#pragma unroll
    for (int i = 0; i < 4; i++)
        tile[ty + i * 8][tx] = in[(size_t)(kb + ty + i * 8) * Npr + nb + tx];
    __syncthreads();
#pragma unroll
    for (int i = 0; i < 4; i++)
        out[(size_t)(nb + ty + i * 8) * K + kb + tx] = f2b(tile[tx][ty + i * 8]);
}

// ---------------- pack conv weights tap-major + zero page ----------------
__global__ __launch_bounds__(256) void k_wtrans(const float* __restrict__ cpe_w,
                                                const float* __restrict__ w3,
                                                const float* __restrict__ w5,
                                                const float* __restrict__ w7,
                                                float* __restrict__ wpk) {
    int idx = blockIdx.x * 256 + threadIdx.x;
    if (idx < 4608) {
        int i = idx / 512, c = idx % 512;
        wpk[idx] = cpe_w[c * 9 + i];
    } else if (idx < 5760) {
        int r = idx - 4608; int i = r / 128, c = r % 128;
        wpk[idx] = w3[c * 9 + i];
    } else if (idx < 10560) {
        int r = idx - 5760; int i = r / 192, c = r % 192;
        wpk[idx] = w5[c * 25 + i];
    } else if (idx < 19968) {
        int r = idx - 10560; int i = r / 192, c = r % 192;
        wpk[idx] = w7[c * 49 + i];
    } else if (idx < WPK_TOTAL) {
        wpk[idx] = 0.f;
    }
}

// ------- Fused ConvPosEnc + LayerNorm1: x0 = dwconv3x3(x)+b+x; cur = LN(x0) -------
__global__ __launch_bounds__(256) void k_cpe_ln(const float* __restrict__ x,
                                                const float* __restrict__ wpk,
                                                const float* __restrict__ bias,
                                                const float* __restrict__ lnw,
                                                const float* __restrict__ lnb,
                                                float* __restrict__ x0,
                                                ushort_t* __restrict__ cur) {
    int t = threadIdx.x;
    int tok = t >> 7;            // 2 tokens per block
    int tl = t & 127;
    int c0 = tl * 4;
    int bb = blockIdx.y;
    int n = blockIdx.x * 2 + tok;
    int y = n / HW, xx = n % HW;
    const float* xb = x + ((size_t)bb * NTOK) * CDIM + c0;
    const float* zf = wpk + 19968;
    float4 a = *(const float4*)(bias + c0);
#pragma unroll
    for (int i = 0; i < 9; i++) {
        int ky = i / 3 - 1, kx = i % 3 - 1;
        int yy = y + ky, xc = xx + kx;
        bool ok = (unsigned)yy < HW && (unsigned)xc < HW;
        const float* ap = ok ? (xb + (size_t)(yy * HW + xc) * CDIM) : zf;
        float4 d = *(const float4*)ap;
        float4 w = *(const float4*)(wpk + i * 512 + c0);
        a.x += w.x * d.x; a.y += w.y * d.y; a.z += w.z * d.z; a.w += w.w * d.w;
    }
    float4 ctr = *(const float4*)(xb + (size_t)n * CDIM);
    a.x += ctr.x; a.y += ctr.y; a.z += ctr.z; a.w += ctr.w;
    *(float4*)(x0 + ((size_t)bb * NTOK + n) * CDIM + c0) = a;

    // LayerNorm over the token's 512 channels
    float s = a.x + a.y + a.z + a.w;
    float s2 = a.x * a.x + a.y * a.y + a.z * a.z + a.w * a.w;
#pragma unroll
    for (int m = 1; m < 64; m <<= 1) { s += __shfl_xor(s, m); s2 += __shfl_xor(s2, m); }
    __shared__ float rs[4], rs2[4];
    int wid = t >> 6, lane = t & 63;
    if (lane == 0) { rs[wid] = s; rs2[wid] = s2; }
    __syncthreads();
    s = rs[tok * 2] + rs[tok * 2 + 1];
    s2 = rs2[tok * 2] + rs2[tok * 2 + 1];
    float mean = s * (1.f / CDIM);
    float var = s2 * (1.f / CDIM) - mean * mean;
    float rstd = rsqrtf(var + 1e-6f);
    float4 wv = *(const float4*)(lnw + c0);
    float4 bv = *(const float4*)(lnb + c0);
    float o0 = (a.x - mean) * rstd * wv.x + bv.x;
    float o1 = (a.y - mean) * rstd * wv.y + bv.y;
    float o2 = (a.z - mean) * rstd * wv.z + bv.z;
    float o3 = (a.w - mean) * rstd * wv.w + bv.w;
    uint2 ro; ro.x = pk2(o0, o1); ro.y = pk2(o2, o3);
    *(uint2*)(cur + ((size_t)bb * NTOK + n) * CDIM + c0) = ro;
}

// -------- LayerNorm over C=512: fp32 in -> bf16 out, one wave per row --------
__global__ __launch_bounds__(256) void k_ln(const float* __restrict__ in,
                                            const float* __restrict__ w,
                                            const float* __restrict__ b,
                                            ushort_t* __restrict__ out) {
    int wid = threadIdx.x >> 6, lane = threadIdx.x & 63;
    size_t row = (size_t)blockIdx.x * 4 + wid;
    const float* p = in + row * CDIM + lane * 8;
    float4 v0 = *(const float4*)p;
    float4 v1 = *(const float4*)(p + 4);
    float v[8] = { v0.x, v0.y, v0.z, v0.w, v1.x, v1.y, v1.z, v1.w };
    float s = 0.f, s2 = 0.f;
#pragma unroll
    for (int i = 0; i < 8; i++) { s += v[i]; s2 += v[i] * v[i]; }
#pragma unroll
    for (int m = 1; m < 64; m <<= 1) { s += __shfl_xor(s, m); s2 += __shfl_xor(s2, m); }
    float mean = s * (1.f / CDIM);
    float var = s2 * (1.f / CDIM) - mean * mean;
    float rstd = rsqrtf(var + 1e-6f);
    float4 w0 = *(const float4*)(w + lane * 8);
    float4 w1 = *(const float4*)(w + lane * 8 + 4);
    float4 b0 = *(const float4*)(b + lane * 8);
    float4 b1 = *(const float4*)(b + lane * 8 + 4);
    float wv[8] = { w0.x, w0.y, w0.z, w0.w, w1.x, w1.y, w1.z, w1.w };
    float bv[8] = { b0.x, b0.y, b0.z, b0.w, b1.x, b1.y, b1.z, b1.w };
    float o[8];
#pragma unroll
    for (int i = 0; i < 8; i++) o[i] = (v[i] - mean) * rstd * wv[i] + bv[i];
    uint4 ro;
    ro.x = pk2(o[0], o[1]); ro.y = pk2(o[2], o[3]); ro.z = pk2(o[4], o[5]); ro.w = pk2(o[6], o[7]);
    *(uint4*)(out + row * CDIM + lane * 8) = ro;
}

// ------------- MFMA GEMM 128x128 (R7-proven): out[M,N] = A[M,K] @ Bt[N,K]^T -------------
// 4 waves, BK=64, single-buffer 32KiB LDS, gload_lds + XOR chunk-swizzle (0 conflicts),
// T1 XCD swizzle. 64V+64A regs -> ~3 blocks/CU; inter-block TLP hides the drain.
// EPI 0: store bf16.  EPI 1: +bias +res(fp32), store fp32.  EPI 2: +bias, GELU(fast), store bf16.
template <int EPI>
__global__ __launch_bounds__(256, 3) void k_gemm(const ushort_t* __restrict__ A,
                                                 const ushort_t* __restrict__ Bt,
                                                 const float* __restrict__ bias,
                                                 const float* __restrict__ res,
                                                 void* __restrict__ outv,
                                                 int M, int Npr, int K) {
    __shared__ ushort_t As[128 * 64];
    __shared__ ushort_t Bs[128 * 64];
    int t = threadIdx.x;

    // XCD-aware chunked swizzle (bijective when nwg%8==0; identity otherwise)
    int gx = gridDim.x;
    int bx = blockIdx.x, by = blockIdx.y;
    int nwg = gx * gridDim.y;
    if ((nwg & 7) == 0) {
        int fid = by * gx + bx;
        int cpx = nwg >> 3;
        int swz = (fid & 7) * cpx + (fid >> 3);
        bx = swz % gx; by = swz / gx;
    }
    int m0 = by * 128, n0 = bx * 128;

    int wid = t >> 6, lane = t & 63, q = lane >> 4, r16 = lane & 15;
    int wr = wid >> 1, wc = wid & 1;     // wave grid 2x2; per-wave out 64x64
    f32x4 acc[4][4] = {};

    int srow = lane >> 3;                    // 0..7 == row&7 at the dest
    int scol = ((lane & 7) ^ srow) * 8;      // pre-swizzled source column
    const ushort_t* pA[4];
    const ushort_t* pB[4];
    int lofs[4];
#pragma unroll
    for (int c = 0; c < 4; c++) {
        int rowc = wid * 32 + c * 8 + srow;          // 0..127
        int ra = m0 + rowc; if (ra > M - 1) ra = M - 1;
        pA[c] = A + (size_t)ra * K + scol;
        pB[c] = Bt + (size_t)(n0 + rowc) * K + scol;
        lofs[c] = (wid * 32 + c * 8) * 64;           // wave-uniform LDS base
    }

    for (int k0 = 0; k0 < K; k0 += 64) {
#pragma unroll
        for (int c = 0; c < 4; c++) gload_lds16(pA[c] + k0, &As[lofs[c]]);
#pragma unroll
        for (int c = 0; c < 4; c++) gload_lds16(pB[c] + k0, &Bs[lofs[c]]);
        __syncthreads();
#pragma unroll
        for (int kk = 0; kk < 64; kk += 32) {
            s16x8 a[4], b[4];
#pragma unroll
            for (int i = 0; i < 4; i++) {
                int R = wr * 64 + i * 16 + r16;
                a[i] = *(const s16x8*)&As[R * 64 + ((kk + q * 8) ^ ((R & 7) * 8))];
            }
#pragma unroll
            for (int j = 0; j < 4; j++) {
                int S = wc * 64 + j * 16 + r16;
                b[j] = *(const s16x8*)&Bs[S * 64 + ((kk + q * 8) ^ ((S & 7) * 8))];
            }
#pragma unroll
            for (int mi = 0; mi < 4; mi++)
#pragma unroll
                for (int ni = 0; ni < 4; ni++)
                    acc[mi][ni] = __builtin_amdgcn_mfma_f32_16x16x32_bf16(a[mi], b[ni], acc[mi][ni], 0, 0, 0);
        }
        __syncthreads();
    }

#pragma unroll
    for (int mi = 0; mi < 4; mi++) {
#pragma unroll
        for (int ni = 0; ni < 4; ni++) {
            int col = n0 + wc * 64 + ni * 16 + r16;
            float bv = 0.f;
            if (EPI != 0) bv = bias[col];
#pragma unroll
            for (int r = 0; r < 4; r++) {
                int row = m0 + wr * 64 + mi * 16 + q * 4 + r;
                if (row >= M) continue;
                float xv = acc[mi][ni][r];
                size_t idx = (size_t)row * Npr + col;
                if (EPI == 0) {
                    ((ushort_t*)outv)[idx] = f2b(xv);
                } else if (EPI == 1) {
                    ((float*)outv)[idx] = xv + bv + res[idx];
                } else {
                    ((ushort_t*)outv)[idx] = f2b(gelu_fast(xv + bv));
                }
            }
        }
    }
}

// ---- kv partial, flash-style: seg-LOCAL softmax(k)^T @ v  (64x64 fp32) ----
// Replaces the separate sm_part pass (51MB k-read + 2 launches): each block
// computes its segment's online max/sum in a cheap pre-pass (14KB of k, L2-hot
// for the immediately following staging loop), exponentiates against the LOCAL
// max, and writes m_seg/s_seg for kv_red to merge (standard flash rescale).
// mxp/ssp layout: [(b*512 + gc)*NSEG + seg]
__global__ __launch_bounds__(256) void k_kv_part(const ushort_t* __restrict__ qkv,
                                                 float* __restrict__ mxp,
                                                 float* __restrict__ ssp,
                                                 float* __restrict__ kvpart) {
    int hd = blockIdx.x, seg = blockIdx.y, b = blockIdx.z;
    int c0 = hd * CH;
    int t = threadIdx.x, tx = t & 15, ty = t >> 4;
    int ch = t & 63, nt4 = t >> 6;
    __shared__ float mx[64];
    __shared__ float ek[8][64];
    __shared__ float vv[8][64];
    __shared__ float redm[4][64], reds[4][64];
    const ushort_t* kbase = qkv + (size_t)b * NTOK * QKVC + CDIM + c0;
    const ushort_t* vbase = kbase + CDIM;
    int nbeg = seg * SEGLEN;

    // pre-pass: per-seg online max & sum over this segment's SEGLEN tokens
    {
        const ushort_t* kb = kbase + ch;
        float m = -1e30f, s = 0.f;
        for (int n = nbeg + nt4; n < nbeg + SEGLEN; n += 4) {
            float v = b2f(kb[(size_t)n * QKVC]);
            float mn = fmaxf(m, v);
            s = s * __expf(m - mn) + __expf(v - mn);
            m = mn;
        }
        redm[nt4][ch] = m; reds[nt4][ch] = s;
    }
    __syncthreads();
    if (t < 64) {
        float m = fmaxf(fmaxf(redm[0][t], redm[1][t]), fmaxf(redm[2][t], redm[3][t]));
        float S = reds[0][t] * __expf(redm[0][t] - m)
                + reds[1][t] * __expf(redm[1][t] - m)
                + reds[2][t] * __expf(redm[2][t] - m)
                + reds[3][t] * __expf(redm[3][t] - m);
        mx[t] = m;
        size_t o = ((size_t)b * CDIM + c0 + t) * NSEG + seg;
        mxp[o] = m;
        ssp[o] = S;
    }
    __syncthreads();

    float acc[4][4] = {};
    for (int n0 = nbeg; n0 < nbeg + SEGLEN; n0 += 8) {
        for (int idx = t; idx < 512; idx += 256) {
            int r = idx >> 6, chh = idx & 63;
            ek[r][chh] = __expf(b2f(kbase[(size_t)(n0 + r) * QKVC + chh]) - mx[chh]);
            vv[r][chh] = b2f(vbase[(size_t)(n0 + r) * QKVC + chh]);
        }
        __syncthreads();
#pragma unroll
        for (int r = 0; r < 8; r++) {
            float ekv[4], vvv[4];
#pragma unroll
            for (int i = 0; i < 4; i++) ekv[i] = ek[r][ty * 4 + i];
#pragma unroll
            for (int j = 0; j < 4; j++) vvv[j] = vv[r][tx * 4 + j];
#pragma unroll
            for (int i = 0; i < 4; i++)
#pragma unroll
                for (int j = 0; j < 4; j++) acc[i][j] += ekv[i] * vvv[j];
        }
        __syncthreads();
    }
    float* outp = kvpart + (((size_t)(b * NHEAD + hd)) * NSEG + seg) * 4096;
#pragma unroll
    for (int i = 0; i < 4; i++)
#pragma unroll
        for (int j = 0; j < 4; j++)
            outp[(size_t)(ty * 4 + i) * CH + tx * 4 + j] = acc[i][j];
}

// ---- kv reduce: flash merge of NSEG local-softmax partials, fold scale/S ----
// kv[ck][cv] = scale/S[ck] * sum_seg kvpart_seg[ck][cv] * exp(m_seg[ck]-m[ck]),
// S[ck] = sum_seg s_seg[ck] * exp(m_seg[ck]-m[ck]).  ef table in LDS (7KB).
__global__ __launch_bounds__(256) void k_kv_red(const float* __restrict__ kvpart,
                                                const float* __restrict__ mxp,
                                                const float* __restrict__ ssp,
                                                float* __restrict__ kv) {
    int quad = blockIdx.x, hd = blockIdx.y, b = blockIdx.z;
    int bh = b * NHEAD + hd;
    int t = threadIdx.x;
    __shared__ float ef[NSEG][64];
    __shared__ float sinv[64];
    if (t < 64) {
        const float* mp = mxp + ((size_t)b * CDIM + hd * CH + t) * NSEG;
        const float* sp = ssp + ((size_t)b * CDIM + hd * CH + t) * NSEG;
        float m = -1e30f;
#pragma unroll 4
        for (int s = 0; s < NSEG; s++) m = fmaxf(m, mp[s]);
        float S = 0.f;
#pragma unroll 4
        for (int s = 0; s < NSEG; s++) {
            float e = __expf(mp[s] - m);
            ef[s][t] = e;
            S += sp[s] * e;
        }
        sinv[t] = 0.125f / S;     // Ch^-0.5 / S
    }
    __syncthreads();
    const float* basep = kvpart + ((size_t)bh * NSEG) * 4096 + quad * 1024;
#pragma unroll
    for (int k = 0; k < 4; k++) {
        int e = k * 256 + t;
        int ck = (quad * 1024 + e) >> 6;
        float s = 0.f;
        for (int sg = 0; sg < NSEG; sg++) s += basep[(size_t)sg * 4096 + e] * ef[sg][ck];
        kv[(size_t)bh * 4096 + quad * 1024 + e] = s * sinv[ck];
    }
}

// ---- ConvRelPosEnc: uniform-KS depthwise conv on v, R4-proven register profile ----
// 4 tokens/thread, rolling tap counter, #pragma unroll 1 (R6's full unroll spilled).
template <int KS>
__global__ __launch_bounds__(KS == 3 ? 256 : 192) void k_conv(const ushort_t* __restrict__ qkv,
                                                              const float* __restrict__ wpk,
                                                              const float* __restrict__ bias,
                                                              ushort_t* __restrict__ conv) {
    constexpr int PAD = KS / 2;
    constexpr int CHBASE = (KS == 3) ? 0 : ((KS == 5) ? 128 : 320);
    constexpr int WBASE = (KS == 3) ? 4608 : ((KS == 5) ? 5760 : 10560);
    constexpr int WSTR = (KS == 3) ? 128 : 192;
    constexpr int GRP = (KS == 3) ? 16 : 24;     // 8-ch groups in this split
    constexpr int LANES = (KS == 3) ? 16 : 8;    // token-lanes per block
    int t = threadIdx.x;
    int g = t % GRP;            // channel group
    int tl = t / GRP;           // token lane
    int bb = blockIdx.y;
    int n0 = blockIdx.x * (LANES * 4) + tl * 4;
    int crel = g * 8;
    const ushort_t* vb = qkv + (size_t)bb * NTOK * QKVC + 2 * CDIM + CHBASE + crel;
    const ushort_t* zp = (const ushort_t*)(wpk + 19968);
    float4 blo = *(const float4*)(bias + crel);
    float4 bhi = *(const float4*)(bias + crel + 4);
    float acc[4][8];
    int ty[4], txx[4];
#pragma unroll
    for (int k4 = 0; k4 < 4; k4++) {
        int n = n0 + k4; ty[k4] = n / HW; txx[k4] = n % HW;
        acc[k4][0] = blo.x; acc[k4][1] = blo.y; acc[k4][2] = blo.z; acc[k4][3] = blo.w;
        acc[k4][4] = bhi.x; acc[k4][5] = bhi.y; acc[k4][6] = bhi.z; acc[k4][7] = bhi.w;
    }
    int ky = -PAD, kx = -PAD;
#pragma unroll 1
    for (int i = 0; i < KS * KS; i++) {
        const float* wp = wpk + WBASE + i * WSTR + crel;
        float4 wlo = *(const float4*)wp;
        float4 whi = *(const float4*)(wp + 4);
        float w[8] = { wlo.x, wlo.y, wlo.z, wlo.w, whi.x, whi.y, whi.z, whi.w };
#pragma unroll
        for (int k4 = 0; k4 < 4; k4++) {
            int yy = ty[k4] + ky, xc = txx[k4] + kx;
            bool ok = (unsigned)yy < HW && (unsigned)xc < HW;
            const ushort_t* ap = ok ? (vb + (size_t)(yy * HW + xc) * QKVC) : zp;
            uint4 d = *(const uint4*)ap;
            float dv[8];
            dv[0] = b2f((ushort_t)(d.x & 0xffff)); dv[1] = b2f((ushort_t)(d.x >> 16));
            dv[2] = b2f((ushort_t)(d.y & 0xffff)); dv[3] = b2f((ushort_t)(d.y >> 16));
            dv[4] = b2f((ushort_t)(d.z & 0xffff)); dv[5] = b2f((ushort_t)(d.z >> 16));
            dv[6] = b2f((ushort_t)(d.w & 0xffff)); dv[7] = b2f((ushort_t)(d.w >> 16));
#pragma unroll
            for (int j = 0; j < 8; j++) acc[k4][j] += w[j] * dv[j];
        }
        kx++; if (kx > PAD) { kx = -PAD; ky++; }
    }
#pragma unroll
    for (int k4 = 0; k4 < 4; k4++) {
        int n = n0 + k4;
        uint4 o;
        o.x = pk2(acc[k4][0], acc[k4][1]);
        o.y = pk2(acc[k4][2], acc[k4][3]);
        o.z = pk2(acc[k4][4], acc[k4][5]);
        o.w = pk2(acc[k4][6], acc[k4][7]);
        *(uint4*)&conv[((size_t)bb * NTOK + n) * CDIM + CHBASE + crel] = o;
    }
}

// ------------- attn = q @ kv + q * conv_v  (overwrites conv buffer, bf16) -------------
__global__ __launch_bounds__(256) void k_attn(const ushort_t* __restrict__ qkv,
                                              const float* __restrict__ kv,
                                              ushort_t* __restrict__ conv) {
    int nb = blockIdx.x, hd = blockIdx.y, b = blockIdx.z;
    int t = threadIdx.x, tx = t & 15, ty = t >> 4;   // ty 0..15
    __shared__ float kvl[64 * 64];    // [ck][cv]
    __shared__ float ql[64 * 65];     // [row][ck], padded
    const float* kvsrc = kv + (size_t)(b * NHEAD + hd) * CH * CH;
    for (int idx = t; idx < 4096; idx += 256) kvl[idx] = kvsrc[idx];
    const ushort_t* qbase = qkv + ((size_t)b * NTOK + nb * 64) * QKVC + hd * CH;
    for (int idx = t; idx < 4096; idx += 256) {
        int r = idx >> 6, ck = idx & 63;
        ql[r * 65 + ck] = b2f(qbase[(size_t)r * QKVC + ck]);
    }
    __syncthreads();
    float acc[4][4] = {};
    for (int ck = 0; ck < 64; ck++) {
        float kvr[4];
#pragma unroll
        for (int j = 0; j < 4; j++) kvr[j] = kvl[ck * 64 + tx * 4 + j];
#pragma unroll
        for (int i = 0; i < 4; i++) {
            float qv = ql[(ty + 16 * i) * 65 + ck];
#pragma unroll
            for (int j = 0; j < 4; j++) acc[i][j] += qv * kvr[j];
        }
    }
    size_t obase = (size_t)b * NTOK + nb * 64;
#pragma unroll
    for (int i = 0; i < 4; i++) {
        int row = ty + 16 * i;
        size_t o = (obase + row) * CDIM + hd * CH + tx * 4;
        uint2 cv = *(const uint2*)&conv[o];
        float c0 = b2f((ushort_t)(cv.x & 0xffff)), c1 = b2f((ushort_t)(cv.x >> 16));
        float c2 = b2f((ushort_t)(cv.y & 0xffff)), c3 = b2f((ushort_t)(cv.y >> 16));
        float q0 = ql[row * 65 + tx * 4 + 0];
        float q1 = ql[row * 65 + tx * 4 + 1];
        float q2 = ql[row * 65 + tx * 4 + 2];
        float q3 = ql[row * 65 + tx * 4 + 3];
        uint2 ov;
        ov.x = pk2(acc[i][0] + q0 * c0, acc[i][1] + q1 * c1);
        ov.y = pk2(acc[i][2] + q2 * c2, acc[i][3] + q3 * c3);
        *(uint2*)&conv[o] = ov;
    }
}

// ---------------------------------------------------------------------------
extern "C" void kernel_launch(void* const* d_in, const int* in_sizes, int n_in,
                              void* d_out, int out_size, void* d_ws, size_t ws_size,
                              hipStream_t stream) {
    const float* x     = (const float*)d_in[0];
    const float* cpe_w = (const float*)d_in[3];
    const float* cpe_b = (const float*)d_in[4];
    const float* ln1_w = (const float*)d_in[5];
    const float* ln1_b = (const float*)d_in[6];
    const float* qkv_w = (const float*)d_in[7];
    const float* proj_w = (const float*)d_in[8];
    const float* proj_b = (const float*)d_in[9];
    const float* w3 = (const float*)d_in[10];
    const float* b3 = (const float*)d_in[11];
    const float* w5 = (const float*)d_in[12];
    const float* b5 = (const float*)d_in[13];
    const float* w7 = (const float*)d_in[14];
    const float* b7 = (const float*)d_in[15];
    const float* ln2_w = (const float*)d_in[16];
    const float* ln2_b = (const float*)d_in[17];
    const float* fc1_w = (const float*)d_in[18];
    const float* fc1_b = (const float*)d_in[19];
    const float* fc2_w = (const float*)d_in[20];
    const float* fc2_b = (const float*)d_in[21];
    float* out = (float*)d_out;

    char* p = (char*)d_ws;
    ushort_t* wt_qkv  = (ushort_t*)p; p += (size_t)QKVC * CDIM * 2;
    ushort_t* wt_proj = (ushort_t*)p; p += (size_t)CDIM * CDIM * 2;
    ushort_t* wt_fc1  = (ushort_t*)p; p += (size_t)HID * CDIM * 2;
    ushort_t* wt_fc2  = (ushort_t*)p; p += (size_t)CDIM * HID * 2;
    float* wpk = (float*)p; p += 20480 * 4;   // WPK_TOTAL rounded up
    size_t wt_bytes = (size_t)(p - (char*)d_ws);

    k_transpose<<<dim3(QKVC / 32, CDIM / 32), 256, 0, stream>>>(qkv_w, wt_qkv, CDIM, QKVC);
    k_transpose<<<dim3(CDIM / 32, CDIM / 32), 256, 0, stream>>>(proj_w, wt_proj, CDIM, CDIM);
    k_transpose<<<dim3(HID / 32, CDIM / 32), 256, 0, stream>>>(fc1_w, wt_fc1, CDIM, HID);
    k_transpose<<<dim3(CDIM / 32, HID / 32), 256, 0, stream>>>(fc2_w, wt_fc2, HID, CDIM);
    k_wtrans<<<(WPK_TOTAL + 255) / 256, 256, 0, stream>>>(cpe_w, w3, w5, w7, wpk);

    // per-batch bytes
    const size_t per_b = (size_t)NTOK * CDIM * 2               // cur
                       + (size_t)NTOK * HID * 2                // union{conv+qkvb | hid}
                       + (size_t)NHEAD * CH * CH * 4           // kv
                       + (size_t)NHEAD * NSEG * 4096 * 4       // kvpart
                       + (size_t)CDIM * NSEG * 4 * 2;          // mxp, ssp
    int Bc = 16;
    while (Bc > 1 && wt_bytes + (size_t)Bc * per_b > ws_size) Bc >>= 1;

    ushort_t* cur = (ushort_t*)p; p += (size_t)Bc * NTOK * CDIM * 2;
    char* un = p;                 p += (size_t)Bc * NTOK * HID * 2;
    ushort_t* conv = (ushort_t*)un;
    ushort_t* qkvb = (ushort_t*)(un + (size_t)Bc * NTOK * CDIM * 2);
    ushort_t* hid  = (ushort_t*)un;
    float* kvb    = (float*)p; p += (size_t)Bc * NHEAD * CH * CH * 4;
    float* kvpart = (float*)p; p += (size_t)Bc * NHEAD * NSEG * 4096 * 4;
    float* mxp = (float*)p; p += (size_t)Bc * CDIM * NSEG * 4;
    float* ssp = (float*)p;

    for (int b0 = 0; b0 < 16; b0 += Bc) {
        int M = Bc * NTOK;
        int gy = (M + 127) / 128;
        const float* xch = x + (size_t)b0 * NTOK * CDIM;
        float* och = out + (size_t)b0 * NTOK * CDIM;
        float* x0 = och;   // fp32 residual backbone lives in the output chunk

        k_cpe_ln<<<dim3(NTOK / 2, Bc), 256, 0, stream>>>(xch, wpk, cpe_b, ln1_w, ln1_b, x0, cur);
        k_gemm<0><<<dim3(QKVC / 128, gy), 256, 0, stream>>>(cur, wt_qkv, nullptr, nullptr, qkvb, M, QKVC, CDIM);
        k_kv_part<<<dim3(NHEAD, NSEG, Bc), 256, 0, stream>>>(qkvb, mxp, ssp, kvpart);
        k_kv_red<<<dim3(4, NHEAD, Bc), 256, 0, stream>>>(kvpart, mxp, ssp, kvb);
        k_conv<3><<<dim3(NTOK / 64, Bc), 256, 0, stream>>>(qkvb, wpk, b3, conv);
        k_conv<5><<<dim3(NTOK / 32, Bc), 192, 0, stream>>>(qkvb, wpk, b5, conv);
        k_conv<7><<<dim3(NTOK / 32, Bc), 192, 0, stream>>>(qkvb, wpk, b7, conv);
        k_attn<<<dim3(NTOK / 64, NHEAD, Bc), 256, 0, stream>>>(qkvb, kvb, conv);
        k_gemm<1><<<dim3(CDIM / 128, gy), 256, 0, stream>>>(conv, wt_proj, proj_b, x0, x0, M, CDIM, CDIM);
        k_ln<<<M / 4, 256, 0, stream>>>(x0, ln2_w, ln2_b, cur);
        k_gemm<2><<<dim3(HID / 128, gy), 256, 0, stream>>>(cur, wt_fc1, fc1_b, nullptr, hid, M, HID, CDIM);
        k_gemm<1><<<dim3(CDIM / 128, gy), 256, 0, stream>>>(hid, wt_fc2, fc2_b, x0, och, M, CDIM, HID);
    }
}

// Round 15
// 1208.681 us; speedup vs baseline: 1.0298x; 1.0015x over previous
//
#include <hip/hip_runtime.h>
#include <hip/hip_bf16.h>

typedef unsigned short ushort_t;
typedef unsigned int uint_t;

typedef float f32x4 __attribute__((ext_vector_type(4)));
typedef short s16x8 __attribute__((ext_vector_type(8)));

#define HW 56
#define NTOK 3136           // 56*56
#define CDIM 512
#define NHEAD 8
#define CH 64
#define QKVC 1536
#define HID 2048
#define NSEG 14
#define SEGLEN 224          // NTOK / NSEG

// packed tap-major weight buffer layout (floats):
// [0,4608)      cpe 3x3:  [i*512 + c]           i<9,  c<512
// [4608,5760)   crpe 3x3: [4608 + i*128 + c]    i<9,  c<128
// [5760,10560)  crpe 5x5: [5760 + i*192 + c]    i<25, c<192
// [10560,19968) crpe 7x7: [10560 + i*192 + c]   i<49, c<192
// [19968,19976) zeros (zero-page for OOB loads)
#define WPK_TOTAL 19976

__device__ __forceinline__ float b2f(ushort_t u) {
    union { uint_t i; float f; } cv; cv.i = ((uint_t)u) << 16; return cv.f;
}
__device__ __forceinline__ ushort_t f2b(float f) {
    union { __hip_bfloat16 h; ushort_t u; } cv; cv.h = __float2bfloat16(f); return cv.u;
}
__device__ __forceinline__ uint_t pk2(float a, float b) {
    return (uint_t)f2b(a) | ((uint_t)f2b(b) << 16);
}

// fast GELU (tanh approximation): max abs err vs exact-erf ~1e-3, two orders
// below the 0.03125 absmax budget. R12/R13/R14: fc1 204->197us, FETCH 80->58MB.
__device__ __forceinline__ float gelu_fast(float x) {
    float u = x * 0.7978845608f * (1.f + 0.044715f * x * x);
    u = fminf(fmaxf(u, -10.f), 10.f);          // tanh saturated; avoids inf/inf
    float e = __expf(2.f * u);
    float th = (e - 1.f) / (e + 1.f);
    return 0.5f * x * (1.f + th);
}

// async global->LDS DMA, 16B per lane. LDS dest is wave-uniform base + lane*16.
__device__ __forceinline__ void gload_lds16(const ushort_t* g, ushort_t* l) {
    __builtin_amdgcn_global_load_lds(
        (const __attribute__((address_space(1))) void*)g,
        (__attribute__((address_space(3))) void*)l, 16, 0, 0);
}

// ---------------- transpose W[K][N] (fp32) -> Wt[N][K] (bf16) ----------------
__global__ __launch_bounds__(256) void k_transpose(const float* __restrict__ in,
                                                   ushort_t* __restrict__ out,
                                                   int K, int Npr) {
    __shared__ float tile[32][33];
    int tx = threadIdx.x & 31, ty = threadIdx.x >> 5;   // ty 0..7
    int kb = blockIdx.y * 32, nb = blockIdx.x * 32;
#pragma unroll
    for (int i = 0; i < 4; i++)
        tile[ty + i * 8][tx] = in[(size_t)(kb + ty + i * 8) * Npr + nb + tx];
    __syncthreads();
#pragma unroll
    for (int i = 0; i < 4; i++)
        out[(size_t)(nb + ty + i * 8) * K + kb + tx] = f2b(tile[tx][ty + i * 8]);
}

// ---------------- pack conv weights tap-major + zero page ----------------
__global__ __launch_bounds__(256) void k_wtrans(const float* __restrict__ cpe_w,
                                                const float* __restrict__ w3,
                                                const float* __restrict__ w5,
                                                const float* __restrict__ w7,
                                                float* __restrict__ wpk) {
    int idx = blockIdx.x * 256 + threadIdx.x;
    if (idx < 4608) {
        int i = idx / 512, c = idx % 512;
        wpk[idx] = cpe_w[c * 9 + i];
    } else if (idx < 5760) {
        int r = idx - 4608; int i = r / 128, c = r % 128;
        wpk[idx] = w3[c * 9 + i];
    } else if (idx < 10560) {
        int r = idx - 5760; int i = r / 192, c = r % 192;
        wpk[idx] = w5[c * 25 + i];
    } else if (idx < 19968) {
        int r = idx - 10560; int i = r / 192, c = r % 192;
        wpk[idx] = w7[c * 49 + i];
    } else if (idx < WPK_TOTAL) {
        wpk[idx] = 0.f;
    }
}

// ------- Fused ConvPosEnc + LayerNorm1: x0 = dwconv3x3(x)+b+x; cur = LN(x0) -------
__global__ __launch_bounds__(256) void k_cpe_ln(const float* __restrict__ x,
                                                const float* __restrict__ wpk,
                                                const float* __restrict__ bias,
                                                const float* __restrict__ lnw,
                                                const float* __restrict__ lnb,
                                                float* __restrict__ x0,
                                                ushort_t* __restrict__ cur) {
    int t = threadIdx.x;
    int tok = t >> 7;            // 2 tokens per block
    int tl = t & 127;
    int c0 = tl * 4;
    int bb = blockIdx.y;
    int n = blockIdx.x * 2 + tok;
    int y = n / HW, xx = n % HW;
    const float* xb = x + ((size_t)bb * NTOK) * CDIM + c0;
    const float* zf = wpk + 19968;
    float4 a = *(const float4*)(bias + c0);
#pragma unroll
    for (int i = 0; i < 9; i++) {
        int ky = i / 3 - 1, kx = i % 3 - 1;
        int yy = y + ky, xc = xx + kx;
        bool ok = (unsigned)yy < HW && (unsigned)xc < HW;
        const float* ap = ok ? (xb + (size_t)(yy * HW + xc) * CDIM) : zf;
        float4 d = *(const float4*)ap;
        float4 w = *(const float4*)(wpk + i * 512 + c0);
        a.x += w.x * d.x; a.y += w.y * d.y; a.z += w.z * d.z; a.w += w.w * d.w;
    }
    float4 ctr = *(const float4*)(xb + (size_t)n * CDIM);
    a.x += ctr.x; a.y += ctr.y; a.z += ctr.z; a.w += ctr.w;
    *(float4*)(x0 + ((size_t)bb * NTOK + n) * CDIM + c0) = a;

    // LayerNorm over the token's 512 channels
    float s = a.x + a.y + a.z + a.w;
    float s2 = a.x * a.x + a.y * a.y + a.z * a.z + a.w * a.w;
#pragma unroll
    for (int m = 1; m < 64; m <<= 1) { s += __shfl_xor(s, m); s2 += __shfl_xor(s2, m); }
    __shared__ float rs[4], rs2[4];
    int wid = t >> 6, lane = t & 63;
    if (lane == 0) { rs[wid] = s; rs2[wid] = s2; }
    __syncthreads();
    s = rs[tok * 2] + rs[tok * 2 + 1];
    s2 = rs2[tok * 2] + rs2[tok * 2 + 1];
    float mean = s * (1.f / CDIM);
    float var = s2 * (1.f / CDIM) - mean * mean;
    float rstd = rsqrtf(var + 1e-6f);
    float4 wv = *(const float4*)(lnw + c0);
    float4 bv = *(const float4*)(lnb + c0);
    float o0 = (a.x - mean) * rstd * wv.x + bv.x;
    float o1 = (a.y - mean) * rstd * wv.y + bv.y;
    float o2 = (a.z - mean) * rstd * wv.z + bv.z;
    float o3 = (a.w - mean) * rstd * wv.w + bv.w;
    uint2 ro; ro.x = pk2(o0, o1); ro.y = pk2(o2, o3);
    *(uint2*)(cur + ((size_t)bb * NTOK + n) * CDIM + c0) = ro;
}

// -------- LayerNorm over C=512: fp32 in -> bf16 out, one wave per row --------
__global__ __launch_bounds__(256) void k_ln(const float* __restrict__ in,
                                            const float* __restrict__ w,
                                            const float* __restrict__ b,
                                            ushort_t* __restrict__ out) {
    int wid = threadIdx.x >> 6, lane = threadIdx.x & 63;
    size_t row = (size_t)blockIdx.x * 4 + wid;
    const float* p = in + row * CDIM + lane * 8;
    float4 v0 = *(const float4*)p;
    float4 v1 = *(const float4*)(p + 4);
    float v[8] = { v0.x, v0.y, v0.z, v0.w, v1.x, v1.y, v1.z, v1.w };
    float s = 0.f, s2 = 0.f;
#pragma unroll
    for (int i = 0; i < 8; i++) { s += v[i]; s2 += v[i] * v[i]; }
#pragma unroll
    for (int m = 1; m < 64; m <<= 1) { s += __shfl_xor(s, m); s2 += __shfl_xor(s2, m); }
    float mean = s * (1.f / CDIM);
    float var = s2 * (1.f / CDIM) - mean * mean;
    float rstd = rsqrtf(var + 1e-6f);
    float4 w0 = *(const float4*)(w + lane * 8);
    float4 w1 = *(const float4*)(w + lane * 8 + 4);
    float4 b0 = *(const float4*)(b + lane * 8);
    float4 b1 = *(const float4*)(b + lane * 8 + 4);
    float wv[8] = { w0.x, w0.y, w0.z, w0.w, w1.x, w1.y, w1.z, w1.w };
    float bv[8] = { b0.x, b0.y, b0.z, b0.w, b1.x, b1.y, b1.z, b1.w };
    float o[8];
#pragma unroll
    for (int i = 0; i < 8; i++) o[i] = (v[i] - mean) * rstd * wv[i] + bv[i];
    uint4 ro;
    ro.x = pk2(o[0], o[1]); ro.y = pk2(o[2], o[3]); ro.z = pk2(o[4], o[5]); ro.w = pk2(o[6], o[7]);
    *(uint4*)(out + row * CDIM + lane * 8) = ro;
}

// ------------- MFMA GEMM 128x128 (R7-proven): out[M,N] = A[M,K] @ Bt[N,K]^T -------------
// 4 waves, BK=64, single-buffer 32KiB LDS, gload_lds + XOR chunk-swizzle (0 conflicts),
// T1 XCD swizzle. 64V+64A regs -> ~3 blocks/CU; inter-block TLP hides the drain.
// EPI 0: store bf16.  EPI 1: +bias +res(fp32), store fp32.  EPI 2: +bias, GELU(fast), store bf16.
template <int EPI>
__global__ __launch_bounds__(256, 3) void k_gemm(const ushort_t* __restrict__ A,
                                                 const ushort_t* __restrict__ Bt,
                                                 const float* __restrict__ bias,
                                                 const float* __restrict__ res,
                                                 void* __restrict__ outv,
                                                 int M, int Npr, int K) {
    __shared__ ushort_t As[128 * 64];
    __shared__ ushort_t Bs[128 * 64];
    int t = threadIdx.x;

    // XCD-aware chunked swizzle (bijective when nwg%8==0; identity otherwise)
    int gx = gridDim.x;
    int bx = blockIdx.x, by = blockIdx.y;
    int nwg = gx * gridDim.y;
    if ((nwg & 7) == 0) {
        int fid = by * gx + bx;
        int cpx = nwg >> 3;
        int swz = (fid & 7) * cpx + (fid >> 3);
        bx = swz % gx; by = swz / gx;
    }
    int m0 = by * 128, n0 = bx * 128;

    int wid = t >> 6, lane = t & 63, q = lane >> 4, r16 = lane & 15;
    int wr = wid >> 1, wc = wid & 1;     // wave grid 2x2; per-wave out 64x64
    f32x4 acc[4][4] = {};

    int srow = lane >> 3;                    // 0..7 == row&7 at the dest
    int scol = ((lane & 7) ^ srow) * 8;      // pre-swizzled source column
    const ushort_t* pA[4];
    const ushort_t* pB[4];
    int lofs[4];
#pragma unroll
    for (int c = 0; c < 4; c++) {
        int rowc = wid * 32 + c * 8 + srow;          // 0..127
        int ra = m0 + rowc; if (ra > M - 1) ra = M - 1;
        pA[c] = A + (size_t)ra * K + scol;
        pB[c] = Bt + (size_t)(n0 + rowc) * K + scol;
        lofs[c] = (wid * 32 + c * 8) * 64;           // wave-uniform LDS base
    }

    for (int k0 = 0; k0 < K; k0 += 64) {
#pragma unroll
        for (int c = 0; c < 4; c++) gload_lds16(pA[c] + k0, &As[lofs[c]]);
#pragma unroll
        for (int c = 0; c < 4; c++) gload_lds16(pB[c] + k0, &Bs[lofs[c]]);
        __syncthreads();
#pragma unroll
        for (int kk = 0; kk < 64; kk += 32) {
            s16x8 a[4], b[4];
#pragma unroll
            for (int i = 0; i < 4; i++) {
                int R = wr * 64 + i * 16 + r16;
                a[i] = *(const s16x8*)&As[R * 64 + ((kk + q * 8) ^ ((R & 7) * 8))];
            }
#pragma unroll
            for (int j = 0; j < 4; j++) {
                int S = wc * 64 + j * 16 + r16;
                b[j] = *(const s16x8*)&Bs[S * 64 + ((kk + q * 8) ^ ((S & 7) * 8))];
            }
#pragma unroll
            for (int mi = 0; mi < 4; mi++)
#pragma unroll
                for (int ni = 0; ni < 4; ni++)
                    acc[mi][ni] = __builtin_amdgcn_mfma_f32_16x16x32_bf16(a[mi], b[ni], acc[mi][ni], 0, 0, 0);
        }
        __syncthreads();
    }

#pragma unroll
    for (int mi = 0; mi < 4; mi++) {
#pragma unroll
        for (int ni = 0; ni < 4; ni++) {
            int col = n0 + wc * 64 + ni * 16 + r16;
            float bv = 0.f;
            if (EPI != 0) bv = bias[col];
#pragma unroll
            for (int r = 0; r < 4; r++) {
                int row = m0 + wr * 64 + mi * 16 + q * 4 + r;
                if (row >= M) continue;
                float xv = acc[mi][ni][r];
                size_t idx = (size_t)row * Npr + col;
                if (EPI == 0) {
                    ((ushort_t*)outv)[idx] = f2b(xv);
                } else if (EPI == 1) {
                    ((float*)outv)[idx] = xv + bv + res[idx];
                } else {
                    ((ushort_t*)outv)[idx] = f2b(gelu_fast(xv + bv));
                }
            }
        }
    }
}

// ---- kv partial, flash-style: seg-LOCAL softmax(k)^T @ v  (64x64 fp32) ----
// R14-proven: per-seg online max/sum pre-pass (k slice L2-hot for the staging
// loop that follows), exponentiate against the LOCAL max, write m_seg/s_seg
// for kv_red's flash merge. NSEG=14 (vs R14's 28): halves kvpart round-trip
// (58.7->29.4MB) — numerically free under local softmax.
// mxp/ssp layout: [(b*512 + gc)*NSEG + seg]
__global__ __launch_bounds__(256) void k_kv_part(const ushort_t* __restrict__ qkv,
                                                 float* __restrict__ mxp,
                                                 float* __restrict__ ssp,
                                                 float* __restrict__ kvpart) {
    int hd = blockIdx.x, seg = blockIdx.y, b = blockIdx.z;
    int c0 = hd * CH;
    int t = threadIdx.x, tx = t & 15, ty = t >> 4;
    int ch = t & 63, nt4 = t >> 6;
    __shared__ float mx[64];
    __shared__ float ek[8][64];
    __shared__ float vv[8][64];
    __shared__ float redm[4][64], reds[4][64];
    const ushort_t* kbase = qkv + (size_t)b * NTOK * QKVC + CDIM + c0;
    const ushort_t* vbase = kbase + CDIM;
    int nbeg = seg * SEGLEN;

    // pre-pass: per-seg online max & sum over this segment's SEGLEN tokens
    {
        const ushort_t* kb = kbase + ch;
        float m = -1e30f, s = 0.f;
        for (int n = nbeg + nt4; n < nbeg + SEGLEN; n += 4) {
            float v = b2f(kb[(size_t)n * QKVC]);
            float mn = fmaxf(m, v);
            s = s * __expf(m - mn) + __expf(v - mn);
            m = mn;
        }
        redm[nt4][ch] = m; reds[nt4][ch] = s;
    }
    __syncthreads();
    if (t < 64) {
        float m = fmaxf(fmaxf(redm[0][t], redm[1][t]), fmaxf(redm[2][t], redm[3][t]));
        float S = reds[0][t] * __expf(redm[0][t] - m)
                + reds[1][t] * __expf(redm[1][t] - m)
                + reds[2][t] * __expf(redm[2][t] - m)
                + reds[3][t] * __expf(redm[3][t] - m);
        mx[t] = m;
        size_t o = ((size_t)b * CDIM + c0 + t) * NSEG + seg;
        mxp[o] = m;
        ssp[o] = S;
    }
    __syncthreads();

    float acc[4][4] = {};
    for (int n0 = nbeg; n0 < nbeg + SEGLEN; n0 += 8) {
        for (int idx = t; idx < 512; idx += 256) {
            int r = idx >> 6, chh = idx & 63;
            ek[r][chh] = __expf(b2f(kbase[(size_t)(n0 + r) * QKVC + chh]) - mx[chh]);
            vv[r][chh] = b2f(vbase[(size_t)(n0 + r) * QKVC + chh]);
        }
        __syncthreads();
#pragma unroll
        for (int r = 0; r < 8; r++) {
            float ekv[4], vvv[4];
#pragma unroll
            for (int i = 0; i < 4; i++) ekv[i] = ek[r][ty * 4 + i];
#pragma unroll
            for (int j = 0; j < 4; j++) vvv[j] = vv[r][tx * 4 + j];
#pragma unroll
            for (int i = 0; i < 4; i++)
#pragma unroll
                for (int j = 0; j < 4; j++) acc[i][j] += ekv[i] * vvv[j];
        }
        __syncthreads();
    }
    float* outp = kvpart + (((size_t)(b * NHEAD + hd)) * NSEG + seg) * 4096;
#pragma unroll
    for (int i = 0; i < 4; i++)
#pragma unroll
        for (int j = 0; j < 4; j++)
            outp[(size_t)(ty * 4 + i) * CH + tx * 4 + j] = acc[i][j];
}

// ---- kv reduce: flash merge of NSEG local-softmax partials, fold scale/S ----
// kv[ck][cv] = scale/S[ck] * sum_seg kvpart_seg[ck][cv] * exp(m_seg[ck]-m[ck]),
// S[ck] = sum_seg s_seg[ck] * exp(m_seg[ck]-m[ck]).  ef table in LDS (3.6KB).
__global__ __launch_bounds__(256) void k_kv_red(const float* __restrict__ kvpart,
                                                const float* __restrict__ mxp,
                                                const float* __restrict__ ssp,
                                                float* __restrict__ kv) {
    int quad = blockIdx.x, hd = blockIdx.y, b = blockIdx.z;
    int bh = b * NHEAD + hd;
    int t = threadIdx.x;
    __shared__ float ef[NSEG][64];
    __shared__ float sinv[64];
    if (t < 64) {
        const float* mp = mxp + ((size_t)b * CDIM + hd * CH + t) * NSEG;
        const float* sp = ssp + ((size_t)b * CDIM + hd * CH + t) * NSEG;
        float m = -1e30f;
#pragma unroll 4
        for (int s = 0; s < NSEG; s++) m = fmaxf(m, mp[s]);
        float S = 0.f;
#pragma unroll 4
        for (int s = 0; s < NSEG; s++) {
            float e = __expf(mp[s] - m);
            ef[s][t] = e;
            S += sp[s] * e;
        }
        sinv[t] = 0.125f / S;     // Ch^-0.5 / S
    }
    __syncthreads();
    const float* basep = kvpart + ((size_t)bh * NSEG) * 4096 + quad * 1024;
#pragma unroll
    for (int k = 0; k < 4; k++) {
        int e = k * 256 + t;
        int ck = (quad * 1024 + e) >> 6;
        float s = 0.f;
        for (int sg = 0; sg < NSEG; sg++) s += basep[(size_t)sg * 4096 + e] * ef[sg][ck];
        kv[(size_t)bh * 4096 + quad * 1024 + e] = s * sinv[ck];
    }
}

// ---- ConvRelPosEnc: uniform-KS depthwise conv on v, R4-proven register profile ----
// 4 tokens/thread, rolling tap counter, #pragma unroll 1 (R6's full unroll spilled).
template <int KS>
__global__ __launch_bounds__(KS == 3 ? 256 : 192) void k_conv(const ushort_t* __restrict__ qkv,
                                                              const float* __restrict__ wpk,
                                                              const float* __restrict__ bias,
                                                              ushort_t* __restrict__ conv) {
    constexpr int PAD = KS / 2;
    constexpr int CHBASE = (KS == 3) ? 0 : ((KS == 5) ? 128 : 320);
    constexpr int WBASE = (KS == 3) ? 4608 : ((KS == 5) ? 5760 : 10560);
    constexpr int WSTR = (KS == 3) ? 128 : 192;
    constexpr int GRP = (KS == 3) ? 16 : 24;     // 8-ch groups in this split
    constexpr int LANES = (KS == 3) ? 16 : 8;    // token-lanes per block
    int t = threadIdx.x;
    int g = t % GRP;            // channel group
    int tl = t / GRP;           // token lane
    int bb = blockIdx.y;
    int n0 = blockIdx.x * (LANES * 4) + tl * 4;
    int crel = g * 8;
    const ushort_t* vb = qkv + (size_t)bb * NTOK * QKVC + 2 * CDIM + CHBASE + crel;
    const ushort_t* zp = (const ushort_t*)(wpk + 19968);
    float4 blo = *(const float4*)(bias + crel);
    float4 bhi = *(const float4*)(bias + crel + 4);
    float acc[4][8];
    int ty[4], txx[4];
#pragma unroll
    for (int k4 = 0; k4 < 4; k4++) {
        int n = n0 + k4; ty[k4] = n / HW; txx[k4] = n % HW;
        acc[k4][0] = blo.x; acc[k4][1] = blo.y; acc[k4][2] = blo.z; acc[k4][3] = blo.w;
        acc[k4][4] = bhi.x; acc[k4][5] = bhi.y; acc[k4][6] = bhi.z; acc[k4][7] = bhi.w;
    }
    int ky = -PAD, kx = -PAD;
#pragma unroll 1
    for (int i = 0; i < KS * KS; i++) {
        const float* wp = wpk + WBASE + i * WSTR + crel;
        float4 wlo = *(const float4*)wp;
        float4 whi = *(const float4*)(wp + 4);
        float w[8] = { wlo.x, wlo.y, wlo.z, wlo.w, whi.x, whi.y, whi.z, whi.w };
#pragma unroll
        for (int k4 = 0; k4 < 4; k4++) {
            int yy = ty[k4] + ky, xc = txx[k4] + kx;
            bool ok = (unsigned)yy < HW && (unsigned)xc < HW;
            const ushort_t* ap = ok ? (vb + (size_t)(yy * HW + xc) * QKVC) : zp;
            uint4 d = *(const uint4*)ap;
            float dv[8];
            dv[0] = b2f((ushort_t)(d.x & 0xffff)); dv[1] = b2f((ushort_t)(d.x >> 16));
            dv[2] = b2f((ushort_t)(d.y & 0xffff)); dv[3] = b2f((ushort_t)(d.y >> 16));
            dv[4] = b2f((ushort_t)(d.z & 0xffff)); dv[5] = b2f((ushort_t)(d.z >> 16));
            dv[6] = b2f((ushort_t)(d.w & 0xffff)); dv[7] = b2f((ushort_t)(d.w >> 16));
#pragma unroll
            for (int j = 0; j < 8; j++) acc[k4][j] += w[j] * dv[j];
        }
        kx++; if (kx > PAD) { kx = -PAD; ky++; }
    }
#pragma unroll
    for (int k4 = 0; k4 < 4; k4++) {
        int n = n0 + k4;
        uint4 o;
        o.x = pk2(acc[k4][0], acc[k4][1]);
        o.y = pk2(acc[k4][2], acc[k4][3]);
        o.z = pk2(acc[k4][4], acc[k4][5]);
        o.w = pk2(acc[k4][6], acc[k4][7]);
        *(uint4*)&conv[((size_t)bb * NTOK + n) * CDIM + CHBASE + crel] = o;
    }
}

// ------------- attn = q @ kv + q * conv_v  (overwrites conv buffer, bf16) -------------
__global__ __launch_bounds__(256) void k_attn(const ushort_t* __restrict__ qkv,
                                              const float* __restrict__ kv,
                                              ushort_t* __restrict__ conv) {
    int nb = blockIdx.x, hd = blockIdx.y, b = blockIdx.z;
    int t = threadIdx.x, tx = t & 15, ty = t >> 4;   // ty 0..15
    __shared__ float kvl[64 * 64];    // [ck][cv]
    __shared__ float ql[64 * 65];     // [row][ck], padded
    const float* kvsrc = kv + (size_t)(b * NHEAD + hd) * CH * CH;
    for (int idx = t; idx < 4096; idx += 256) kvl[idx] = kvsrc[idx];
    const ushort_t* qbase = qkv + ((size_t)b * NTOK + nb * 64) * QKVC + hd * CH;
    for (int idx = t; idx < 4096; idx += 256) {
        int r = idx >> 6, ck = idx & 63;
        ql[r * 65 + ck] = b2f(qbase[(size_t)r * QKVC + ck]);
    }
    __syncthreads();
    float acc[4][4] = {};
    for (int ck = 0; ck < 64; ck++) {
        float kvr[4];
#pragma unroll
        for (int j = 0; j < 4; j++) kvr[j] = kvl[ck * 64 + tx * 4 + j];
#pragma unroll
        for (int i = 0; i < 4; i++) {
            float qv = ql[(ty + 16 * i) * 65 + ck];
#pragma unroll
            for (int j = 0; j < 4; j++) acc[i][j] += qv * kvr[j];
        }
    }
    size_t obase = (size_t)b * NTOK + nb * 64;
#pragma unroll
    for (int i = 0; i < 4; i++) {
        int row = ty + 16 * i;
        size_t o = (obase + row) * CDIM + hd * CH + tx * 4;
        uint2 cv = *(const uint2*)&conv[o];
        float c0 = b2f((ushort_t)(cv.x & 0xffff)), c1 = b2f((ushort_t)(cv.x >> 16));
        float c2 = b2f((ushort_t)(cv.y & 0xffff)), c3 = b2f((ushort_t)(cv.y >> 16));
        float q0 = ql[row * 65 + tx * 4 + 0];
        float q1 = ql[row * 65 + tx * 4 + 1];
        float q2 = ql[row * 65 + tx * 4 + 2];
        float q3 = ql[row * 65 + tx * 4 + 3];
        uint2 ov;
        ov.x = pk2(acc[i][0] + q0 * c0, acc[i][1] + q1 * c1);
        ov.y = pk2(acc[i][2] + q2 * c2, acc[i][3] + q3 * c3);
        *(uint2*)&conv[o] = ov;
    }
}

// ---------------------------------------------------------------------------
extern "C" void kernel_launch(void* const* d_in, const int* in_sizes, int n_in,
                              void* d_out, int out_size, void* d_ws, size_t ws_size,
                              hipStream_t stream) {
    const float* x     = (const float*)d_in[0];
    const float* cpe_w = (const float*)d_in[3];
    const float* cpe_b = (const float*)d_in[4];
    const float* ln1_w = (const float*)d_in[5];
    const float* ln1_b = (const float*)d_in[6];
    const float* qkv_w = (const float*)d_in[7];
    const float* proj_w = (const float*)d_in[8];
    const float* proj_b = (const float*)d_in[9];
    const float* w3 = (const float*)d_in[10];
    const float* b3 = (const float*)d_in[11];
    const float* w5 = (const float*)d_in[12];
    const float* b5 = (const float*)d_in[13];
    const float* w7 = (const float*)d_in[14];
    const float* b7 = (const float*)d_in[15];
    const float* ln2_w = (const float*)d_in[16];
    const float* ln2_b = (const float*)d_in[17];
    const float* fc1_w = (const float*)d_in[18];
    const float* fc1_b = (const float*)d_in[19];
    const float* fc2_w = (const float*)d_in[20];
    const float* fc2_b = (const float*)d_in[21];
    float* out = (float*)d_out;

    char* p = (char*)d_ws;
    ushort_t* wt_qkv  = (ushort_t*)p; p += (size_t)QKVC * CDIM * 2;
    ushort_t* wt_proj = (ushort_t*)p; p += (size_t)CDIM * CDIM * 2;
    ushort_t* wt_fc1  = (ushort_t*)p; p += (size_t)HID * CDIM * 2;
    ushort_t* wt_fc2  = (ushort_t*)p; p += (size_t)CDIM * HID * 2;
    float* wpk = (float*)p; p += 20480 * 4;   // WPK_TOTAL rounded up
    size_t wt_bytes = (size_t)(p - (char*)d_ws);

    k_transpose<<<dim3(QKVC / 32, CDIM / 32), 256, 0, stream>>>(qkv_w, wt_qkv, CDIM, QKVC);
    k_transpose<<<dim3(CDIM / 32, CDIM / 32), 256, 0, stream>>>(proj_w, wt_proj, CDIM, CDIM);
    k_transpose<<<dim3(HID / 32, CDIM / 32), 256, 0, stream>>>(fc1_w, wt_fc1, CDIM, HID);
    k_transpose<<<dim3(CDIM / 32, HID / 32), 256, 0, stream>>>(fc2_w, wt_fc2, HID, CDIM);
    k_wtrans<<<(WPK_TOTAL + 255) / 256, 256, 0, stream>>>(cpe_w, w3, w5, w7, wpk);

    // per-batch bytes
    const size_t per_b = (size_t)NTOK * CDIM * 2               // cur
                       + (size_t)NTOK * HID * 2                // union{conv+qkvb | hid}
                       + (size_t)NHEAD * CH * CH * 4           // kv
                       + (size_t)NHEAD * NSEG * 4096 * 4       // kvpart
                       + (size_t)CDIM * NSEG * 4 * 2;          // mxp, ssp
    int Bc = 16;
    while (Bc > 1 && wt_bytes + (size_t)Bc * per_b > ws_size) Bc >>= 1;

    ushort_t* cur = (ushort_t*)p; p += (size_t)Bc * NTOK * CDIM * 2;
    char* un = p;                 p += (size_t)Bc * NTOK * HID * 2;
    ushort_t* conv = (ushort_t*)un;
    ushort_t* qkvb = (ushort_t*)(un + (size_t)Bc * NTOK * CDIM * 2);
    ushort_t* hid  = (ushort_t*)un;
    float* kvb    = (float*)p; p += (size_t)Bc * NHEAD * CH * CH * 4;
    float* kvpart = (float*)p; p += (size_t)Bc * NHEAD * NSEG * 4096 * 4;
    float* mxp = (float*)p; p += (size_t)Bc * CDIM * NSEG * 4;
    float* ssp = (float*)p;

    for (int b0 = 0; b0 < 16; b0 += Bc) {
        int M = Bc * NTOK;
        int gy = (M + 127) / 128;
        const float* xch = x + (size_t)b0 * NTOK * CDIM;
        float* och = out + (size_t)b0 * NTOK * CDIM;
        float* x0 = och;   // fp32 residual backbone lives in the output chunk

        k_cpe_ln<<<dim3(NTOK / 2, Bc), 256, 0, stream>>>(xch, wpk, cpe_b, ln1_w, ln1_b, x0, cur);
        k_gemm<0><<<dim3(QKVC / 128, gy), 256, 0, stream>>>(cur, wt_qkv, nullptr, nullptr, qkvb, M, QKVC, CDIM);
        k_kv_part<<<dim3(NHEAD, NSEG, Bc), 256, 0, stream>>>(qkvb, mxp, ssp, kvpart);
        k_kv_red<<<dim3(4, NHEAD, Bc), 256, 0, stream>>>(kvpart, mxp, ssp, kvb);
        k_conv<3><<<dim3(NTOK / 64, Bc), 256, 0, stream>>>(qkvb, wpk, b3, conv);
        k_conv<5><<<dim3(NTOK / 32, Bc), 192, 0, stream>>>(qkvb, wpk, b5, conv);
        k_conv<7><<<dim3(NTOK / 32, Bc), 192, 0, stream>>>(qkvb, wpk, b7, conv);
        k_attn<<<dim3(NTOK / 64, NHEAD, Bc), 256, 0, stream>>>(qkvb, kvb, conv);
        k_gemm<1><<<dim3(CDIM / 128, gy), 256, 0, stream>>>(conv, wt_proj, proj_b, x0, x0, M, CDIM, CDIM);
        k_ln<<<M / 4, 256, 0, stream>>>(x0, ln2_w, ln2_b, cur);
        k_gemm<2><<<dim3(HID / 128, gy), 256, 0, stream>>>(cur, wt_fc1, fc1_b, nullptr, hid, M, HID, CDIM);
        k_gemm<1><<<dim3(CDIM / 128, gy), 256, 0, stream>>>(hid, wt_fc2, fc2_b, x0, och, M, CDIM, HID);
    }
}